// Round 9
// baseline (88.651 us; speedup 1.0000x reference)
//
#include <hip/hip_runtime.h>
#include <math.h>

#define IOU_THR 0.5f
#define NCNT 8            // counting blocks in prep_kernel
#define SLICES 8          // slices per row (power of 2; blk>>3 below)
#define SENT 0x7fffffff

__device__ __forceinline__ bool better(float va, int ia, float vb, int ib) {
    // lax.top_k ordering: higher value first; ties -> lower index first
    return (va > vb) || (va == vb && ia < ib);
}

// merge two desc-sorted stable top3 triples -> (a*, x*)
__device__ __forceinline__ void merge3(float& a0, float& a1, float& a2,
                                       int& x0, int& x1, int& x2,
                                       float b0, float b1, float b2,
                                       int y0, int y1, int y2) {
    bool t0 = better(a0, x0, b0, y0);
    float ov0 = t0 ? a0 : b0;  int oi0 = t0 ? x0 : y0;
    float ahv = t0 ? a1 : a0;  int ahi = t0 ? x1 : x0;
    float a2v = t0 ? a2 : a1;  int a2i = t0 ? x2 : x1;
    float bhv = t0 ? b0 : b1;  int bhi = t0 ? y0 : y1;
    float b2v = t0 ? b1 : b2;  int b2i = t0 ? y1 : y2;
    bool t1 = better(ahv, ahi, bhv, bhi);
    float ov1 = t1 ? ahv : bhv; int oi1 = t1 ? ahi : bhi;
    float cav = t1 ? a2v : ahv; int cai = t1 ? a2i : ahi;
    float cbv = t1 ? bhv : b2v; int cbi = t1 ? bhi : b2i;
    bool t2 = better(cav, cai, cbv, cbi);
    a0 = ov0; a1 = ov1; a2 = t2 ? cav : cbv;
    x0 = oi0; x1 = oi1; x2 = t2 ? cai : cbi;
}

__device__ __forceinline__ float hashf(unsigned x) {
    x *= 2654435761u;
    x ^= x >> 13;
    return __int_as_float(0x3e800000u | (x & 0x007fffffu)); // [0.25, 0.5)
}

// NCNT+1 blocks x 256 threads (unchanged from round 8, minus uniform flag).
__global__ void prep_kernel(const int* __restrict__ num_targets,
                            const int* __restrict__ mask2d,
                            int* __restrict__ scatter,
                            int* __restrict__ counts,
                            int S, int M, int P) {
    const int bid = blockIdx.x;
    const int tid = threadIdx.x;

    if (bid < NCNT) {
        const int P4 = P >> 2;
        const int4* __restrict__ m4 = (const int4*)mask2d;
        int c = 0;
        for (int q = bid * 256 + tid; q < P4; q += NCNT * 256) {
            const int4 v = m4[q];
            c += (v.x != 0) + (v.y != 0) + (v.z != 0) + (v.w != 0);
        }
        if (bid == 0) {
            for (int j = (P4 << 2) + tid; j < P; j += 256)
                c += (mask2d[j] != 0);
        }
        __shared__ int red[256];
        red[tid] = c;
        __syncthreads();
        for (int st = 128; st > 0; st >>= 1) {
            if (tid < st) red[tid] += red[tid + st];
            __syncthreads();
        }
        if (tid == 0) counts[bid] = red[0];
    } else {
        __shared__ int cum[1025];   // supports S <= 1024
        __shared__ int scn[256];
        const int chunk = (S + 255) / 256;
        const int sbase = tid * chunk;
        int local[4];
        int csum = 0;
        for (int k = 0; k < chunk && k < 4; ++k) {
            int s = sbase + k;
            int v = (s < S) ? num_targets[s] : 0;
            csum += v;
            local[k] = csum;
        }
        scn[tid] = csum;
        __syncthreads();
        for (int d = 1; d < 256; d <<= 1) {
            int v = scn[tid];
            int add = (tid >= d) ? scn[tid - d] : 0;
            __syncthreads();
            scn[tid] = v + add;
            __syncthreads();
        }
        {
            int excl = scn[tid] - csum;
            for (int k = 0; k < chunk && k < 4; ++k) {
                int s = sbase + k;
                if (s < S) cum[s + 1] = excl + local[k];
            }
            if (tid == 0) cum[0] = 0;
        }
        __syncthreads();
        const int total = cum[S];
        for (int m = tid; m < M; m += 256) {
            int mm = m;
            if (mm >= total) mm = (total > 0) ? (total - 1) : 0;  // jnp.repeat pad
            int lo = 0, hi = S - 1;
            while (lo < hi) {
                int mid = (lo + hi) >> 1;
                if (cum[mid + 1] <= mm) lo = mid + 1; else hi = mid;
            }
            scatter[m] = lo;
        }
    }
}

// 1 block x 256 threads (unchanged from round 8).
__global__ void build_kernel(const int* __restrict__ counts,
                             const int* __restrict__ mask2d,
                             int* __restrict__ rcidx,
                             float* __restrict__ starts,
                             float* __restrict__ ends,
                             int* __restrict__ flag,
                             int N, int P) {
    const int tid = threadIdx.x;
    __shared__ int scan[256];

    scan[tid] = (tid < NCNT) ? counts[tid] : 0;
    __syncthreads();
    for (int st = 128; st > 0; st >>= 1) {
        if (tid < st) scan[tid] += scan[tid + st];
        __syncthreads();
    }
    const int K_all = scan[0];
    const int f = (K_all == P && (P & 3) == 0 && (N & (N - 1)) == 0 && N >= 4) ? 1 : 0;
    if (tid == 0) flag[0] = f;
    if (f) return;
    __syncthreads();

    const int per = (P + 255) / 256;
    const int base = tid * per;
    int cnt = 0;
    for (int k = 0; k < per; ++k) {
        int j = base + k;
        if (j < P && mask2d[j] != 0) cnt++;
    }
    scan[tid] = cnt;
    __syncthreads();
    for (int d = 1; d < 256; d <<= 1) {
        int v = scan[tid];
        int add = (tid >= d) ? scan[tid - d] : 0;
        __syncthreads();
        scan[tid] = v + add;
        __syncthreads();
    }
    const int K = scan[255];
    int pos = scan[tid] - cnt;

    const float fN = (float)N;
    for (int k = 0; k < per; ++k) {
        int j = base + k;
        if (j < P && mask2d[j] != 0) {
            int r = j / N;
            int c = j - r * N;
            rcidx[pos]  = j;
            starts[pos] = (float)r / fN;
            ends[pos]   = (float)(c + 1) / fN;
            pos++;
        }
    }
    __syncthreads();
    for (int j = K + tid; j < P; j += 256) {
        rcidx[j]  = 0;
        starts[j] = 0.0f;
        ends[j]   = 1.0f / fN;
    }
}

// MODE 0: full per-slice top3 + thresholded sums.
// MODE 1: probe — identical loads, trivial sum only (memory-path isolation).
// MODE 2: probe — no data loads, synthetic values, full PROC chain (VALU-path).
// Grid: M*SLICES blocks x 256 threads; block handles slice sl of row m.
template<int MODE>
__global__ __launch_bounds__(256)
void slice_kernel(const float* __restrict__ start_offset,
                  const float* __restrict__ end_offset,
                  const float* __restrict__ tgt_moments,
                  const int* __restrict__ scatter,
                  const float* __restrict__ iou2ds,
                  const int* __restrict__ rcidx,
                  const float* __restrict__ starts,
                  const float* __restrict__ ends,
                  float* __restrict__ pv, int* __restrict__ pi,
                  double* __restrict__ ps, int* __restrict__ pc,
                  const int* __restrict__ flag,
                  int P, int M, int N) {
    const int blk = blockIdx.x;
    const int m   = blk >> 3;              // SLICES == 8
    const int sl  = blk & (SLICES - 1);
    const int tid = threadIdx.x;
    const int fp  = flag[0];
    const int s   = scatter[m];

    const float* __restrict__ so_row  = start_offset + (size_t)s * P;
    const float* __restrict__ eo_row  = end_offset   + (size_t)s * P;
    const float* __restrict__ iou_row = iou2ds       + (size_t)m * P;
    const float tgt0 = tgt_moments[2 * m];
    const float tgt1 = tgt_moments[2 * m + 1];

    const int   lgN  = 31 - __clz(N);      // valid when fp (N pow2)
    const float invN = 1.0f / (float)N;    // exact for pow2 N

    float v0 = -INFINITY, v1 = -INFINITY, v2 = -INFINITY;
    int   i0 = SENT, i1 = SENT, i2 = SENT;
    float lsum = 0.0f;
    int   lcnt = 0;

#define PROC(v, jj, so_, eo_, A_, B_)                                       \
    do {                                                                    \
        const bool b0 = (v) > v0;                                           \
        const bool b1 = (v) > v1;                                           \
        const bool b2 = (v) > v2;                                           \
        const float nv0 = fmaxf(v0, (v));                                   \
        const float nv1 = __builtin_amdgcn_fmed3f((v), v0, v1);             \
        const float nv2 = __builtin_amdgcn_fmed3f((v), v1, v2);             \
        i2 = b1 ? i1 : (b2 ? (jj) : i2);                                    \
        i1 = b0 ? i0 : (b1 ? (jj) : i1);                                    \
        i0 = b0 ? (jj) : i0;                                                \
        v0 = nv0; v1 = nv1; v2 = nv2;                                       \
        const bool sel = (v) > IOU_THR;                                     \
        const float l_ = fabsf((so_) - (A_)) + fabsf((eo_) - (B_));         \
        lsum += sel ? l_ : 0.0f;                                            \
        lcnt += sel ? 1 : 0;                                                \
    } while (0)

    if (MODE == 2) {
        // synthetic-value probe: same arithmetic chain, zero data loads
        const int P4 = P >> 2;
        const int q4len = (P4 + SLICES - 1) / SLICES;
        const int q0 = sl * q4len;
        const int qe = min(q0 + q4len, P4);
        const unsigned mh = (unsigned)m * 0x9e3779b9u;
        for (int q = q0 + tid; q < qe; q += 256) {
            const int j_ = q << 2;
            const int r_ = j_ >> lgN;
            const int c_ = j_ & (N - 1);
            const float A_  = tgt0 - (float)r_ * invN;
            const float en0 = (float)(c_ + 1) * invN;
            const unsigned u = (unsigned)j_ ^ mh;
            PROC(hashf(u + 0u) * 2.0f, j_ + 0, hashf(u + 11u), hashf(u + 21u), A_, tgt1 - en0);
            PROC(hashf(u + 1u) * 2.0f, j_ + 1, hashf(u + 12u), hashf(u + 22u), A_, tgt1 - (en0 + invN));
            PROC(hashf(u + 2u) * 2.0f, j_ + 2, hashf(u + 13u), hashf(u + 23u), A_, tgt1 - (en0 + 2.0f * invN));
            PROC(hashf(u + 3u) * 2.0f, j_ + 3, hashf(u + 14u), hashf(u + 24u), A_, tgt1 - (en0 + 3.0f * invN));
        }
    } else if (fp) {
        const float4* __restrict__ iou4 = (const float4*)iou_row;
        const float4* __restrict__ so4  = (const float4*)so_row;
        const float4* __restrict__ eo4  = (const float4*)eo_row;
        const int P4 = P >> 2;
        const int q4len = (P4 + SLICES - 1) / SLICES;
        const int q0 = sl * q4len;
        const int qe = min(q0 + q4len, P4);
        for (int q = q0 + tid; q < qe; q += 256) {
            const float4 vi = iou4[q];
            const float4 vs = so4[q];
            const float4 ve = eo4[q];
            if (MODE == 1) {
                // load-only probe: consume everything with cheap adds
                lsum += (vi.x + vi.y + vi.z + vi.w)
                      + (vs.x + vs.y + vs.z + vs.w)
                      + (ve.x + ve.y + ve.z + ve.w);
            } else {
                const int j_ = q << 2;
                const int r_ = j_ >> lgN;
                const int c_ = j_ & (N - 1);
                const float A_  = tgt0 - (float)r_ * invN;
                const float en0 = (float)(c_ + 1) * invN;
                PROC(vi.x, j_ + 0, vs.x, ve.x, A_, tgt1 - en0);
                PROC(vi.y, j_ + 1, vs.y, ve.y, A_, tgt1 - (en0 + invN));
                PROC(vi.z, j_ + 2, vs.z, ve.z, A_, tgt1 - (en0 + 2.0f * invN));
                PROC(vi.w, j_ + 3, vs.w, ve.w, A_, tgt1 - (en0 + 3.0f * invN));
            }
        }
    } else {
        // general path: compacted indices/coords from ws arrays
        const int plen = (P + SLICES - 1) / SLICES;
        const int j0 = sl * plen;
        const int je = min(j0 + plen, P);
        for (int j = j0 + tid; j < je; j += 256) {
            const int   idx = rcidx[j];
            const float v   = iou_row[idx];
            const float A_  = tgt0 - starts[j];
            const float B_  = tgt1 - ends[j];
            if (MODE == 1) { lsum += v + so_row[j] + eo_row[j]; }
            else           { PROC(v, j, so_row[j], eo_row[j], A_, B_); }
        }
    }
#undef PROC

    // ---- block reduction: wave butterflies + cross-wave LDS (4 waves) ----
    if (MODE != 1) {
        for (int d = 1; d < 64; d <<= 1) {
            float b0v = __shfl_xor(v0, d), b1v = __shfl_xor(v1, d), b2v = __shfl_xor(v2, d);
            int   y0 = __shfl_xor(i0, d), y1 = __shfl_xor(i1, d), y2 = __shfl_xor(i2, d);
            merge3(v0, v1, v2, i0, i1, i2, b0v, b1v, b2v, y0, y1, y2);
        }
    }
    double dsum = (double)lsum;
    for (int d = 1; d < 64; d <<= 1) dsum += __shfl_xor(dsum, d);
    for (int d = 1; d < 64; d <<= 1) lcnt += __shfl_xor(lcnt, d);

    __shared__ float  wv[4][3];
    __shared__ int    wi[4][3];
    __shared__ double wsum[4];
    __shared__ int    wcnt[4];
    const int wid  = tid >> 6;
    const int lane = tid & 63;
    if (lane == 0) {
        wv[wid][0] = v0; wv[wid][1] = v1; wv[wid][2] = v2;
        wi[wid][0] = i0; wi[wid][1] = i1; wi[wid][2] = i2;
        wsum[wid] = dsum; wcnt[wid] = lcnt;
    }
    __syncthreads();
    if (tid == 0) {
        float a0 = wv[0][0], a1 = wv[0][1], a2 = wv[0][2];
        int   x0 = wi[0][0], x1 = wi[0][1], x2 = wi[0][2];
        double S = wsum[0];
        int    C = wcnt[0];
        for (int w = 1; w < 4; ++w) {
            merge3(a0, a1, a2, x0, x1, x2,
                   wv[w][0], wv[w][1], wv[w][2],
                   wi[w][0], wi[w][1], wi[w][2]);
            S += wsum[w];
            C += wcnt[w];
        }
        pv[blk * 3 + 0] = a0; pv[blk * 3 + 1] = a1; pv[blk * 3 + 2] = a2;
        pi[blk * 3 + 0] = x0; pi[blk * 3 + 1] = x1; pi[blk * 3 + 2] = x2;
        ps[blk] = S;
        pc[blk] = C;
    }
}

// One thread per row m: merge the SLICES partials, add uncounted top-3 losses.
__global__ void merge_kernel(const float* __restrict__ pv,
                             const int* __restrict__ pi,
                             const double* __restrict__ ps,
                             const int* __restrict__ pc,
                             const float* __restrict__ start_offset,
                             const float* __restrict__ end_offset,
                             const float* __restrict__ tgt_moments,
                             const int* __restrict__ scatter,
                             const float* __restrict__ starts,
                             const float* __restrict__ ends,
                             double* __restrict__ psum,
                             int* __restrict__ pcnt,
                             const int* __restrict__ flag,
                             int P, int M, int N) {
    const int m = blockIdx.x * blockDim.x + threadIdx.x;
    if (m >= M) return;
    const int fp = flag[0];
    const int s  = scatter[m];
    const float* __restrict__ so_row = start_offset + (size_t)s * P;
    const float* __restrict__ eo_row = end_offset   + (size_t)s * P;
    const float tgt0 = tgt_moments[2 * m];
    const float tgt1 = tgt_moments[2 * m + 1];
    const int   lgN  = 31 - __clz(N);
    const float invN = 1.0f / (float)N;

    const int b0 = m * SLICES;
    float a0 = pv[b0 * 3 + 0], a1 = pv[b0 * 3 + 1], a2 = pv[b0 * 3 + 2];
    int   x0 = pi[b0 * 3 + 0], x1 = pi[b0 * 3 + 1], x2 = pi[b0 * 3 + 2];
    double S = ps[b0];
    int    C = pc[b0];
    for (int sl = 1; sl < SLICES; ++sl) {
        const int b = b0 + sl;
        merge3(a0, a1, a2, x0, x1, x2,
               pv[b * 3 + 0], pv[b * 3 + 1], pv[b * 3 + 2],
               pi[b * 3 + 0], pi[b * 3 + 1], pi[b * 3 + 2]);
        S += ps[b];
        C += pc[b];
    }
#define ADDTOP(vk, jk)                                                      \
    do {                                                                    \
        if ((jk) != SENT && !((vk) > IOU_THR)) {                            \
            float st_, en_;                                                 \
            if (fp) {                                                       \
                int r_ = (jk) >> lgN, c_ = (jk) & (N - 1);                  \
                st_ = (float)r_ * invN; en_ = (float)(c_ + 1) * invN;       \
            } else { st_ = starts[jk]; en_ = ends[jk]; }                    \
            S += (double)(fabsf(so_row[jk] - (tgt0 - st_)) +                \
                          fabsf(eo_row[jk] - (tgt1 - en_)));                \
            C += 1;                                                         \
        }                                                                   \
    } while (0)
    ADDTOP(a0, x0);
    ADDTOP(a1, x1);
    ADDTOP(a2, x2);
#undef ADDTOP
    psum[m] = S;
    pcnt[m] = C;
}

__global__ void finalize_kernel(const double* __restrict__ psum,
                                const int* __restrict__ pcnt,
                                int M, float* __restrict__ out) {
    __shared__ double sd[256];
    __shared__ int    sc[256];
    const int tid = threadIdx.x;
    double a = 0.0;
    int    c = 0;
    for (int i = tid; i < M; i += 256) { a += psum[i]; c += pcnt[i]; }
    sd[tid] = a; sc[tid] = c;
    __syncthreads();
    for (int str = 128; str > 0; str >>= 1) {
        if (tid < str) { sd[tid] += sd[tid + str]; sc[tid] += sc[tid + str]; }
        __syncthreads();
    }
    if (tid == 0) out[0] = (float)(sd[0] / (double)sc[0]);
}

extern "C" void kernel_launch(void* const* d_in, const int* in_sizes, int n_in,
                              void* d_out, int out_size, void* d_ws, size_t ws_size,
                              hipStream_t stream) {
    const float* start_offset = (const float*)d_in[0];
    const float* end_offset   = (const float*)d_in[1];
    const float* tgt_moments  = (const float*)d_in[2];
    const int*   num_targets  = (const int*)d_in[3];
    const float* iou2ds       = (const float*)d_in[4];
    const int*   mask2d       = (const int*)d_in[5];   // bool pushed as int32

    const int S = in_sizes[3];
    const int M = in_sizes[2] / 2;
    const int P = in_sizes[0] / S;
    const int NN = in_sizes[5];
    int N = 1;
    while ((long long)N * N < (long long)NN) N++;

    // workspace layout (16B aligned blocks)
    char* ws = (char*)d_ws;
    size_t off = 0;
    const size_t MB = (size_t)M * SLICES;
    int*    flag     = (int*)(ws + off);    off += 16;
    int*    counts   = (int*)(ws + off);    off += (NCNT * 4 + 15) & ~(size_t)15;
    int*    scatter  = (int*)(ws + off);    off += ((size_t)M * 4 + 15) & ~(size_t)15;
    int*    rcidx    = (int*)(ws + off);    off += ((size_t)P * 4 + 15) & ~(size_t)15;
    float*  starts   = (float*)(ws + off);  off += ((size_t)P * 4 + 15) & ~(size_t)15;
    float*  ends     = (float*)(ws + off);  off += ((size_t)P * 4 + 15) & ~(size_t)15;
    double* psum     = (double*)(ws + off); off += ((size_t)M * 8 + 15) & ~(size_t)15;
    int*    pcnt     = (int*)(ws + off);    off += ((size_t)M * 4 + 15) & ~(size_t)15;
    float*  pv       = (float*)(ws + off);  off += (MB * 12 + 15) & ~(size_t)15;
    int*    pi       = (int*)(ws + off);    off += (MB * 12 + 15) & ~(size_t)15;
    double* ps       = (double*)(ws + off); off += (MB * 8 + 15) & ~(size_t)15;
    int*    pc       = (int*)(ws + off);    off += (MB * 4 + 15) & ~(size_t)15;

    prep_kernel<<<NCNT + 1, 256, 0, stream>>>(num_targets, mask2d, scatter, counts,
                                              S, M, P);
    build_kernel<<<1, 256, 0, stream>>>(counts, mask2d, rcidx, starts, ends, flag, N, P);

    // real pipeline
    slice_kernel<0><<<M * SLICES, 256, 0, stream>>>(start_offset, end_offset,
        tgt_moments, scatter, iou2ds, rcidx, starts, ends, pv, pi, ps, pc, flag, P, M, N);
    merge_kernel<<<(M + 255) / 256, 256, 0, stream>>>(pv, pi, ps, pc,
        start_offset, end_offset, tgt_moments, scatter, starts, ends,
        psum, pcnt, flag, P, M, N);
    finalize_kernel<<<1, 256, 0, stream>>>(psum, pcnt, M, (float*)d_out);

    // diagnostic probes (outputs overwritten into the same partial arrays,
    // AFTER merge consumed them — deterministic, d_out unaffected)
    slice_kernel<1><<<M * SLICES, 256, 0, stream>>>(start_offset, end_offset,
        tgt_moments, scatter, iou2ds, rcidx, starts, ends, pv, pi, ps, pc, flag, P, M, N);
    slice_kernel<2><<<M * SLICES, 256, 0, stream>>>(start_offset, end_offset,
        tgt_moments, scatter, iou2ds, rcidx, starts, ends, pv, pi, ps, pc, flag, P, M, N);
}

// Round 10
// 42.613 us; speedup vs baseline: 2.0804x; 2.0804x over previous
//
#include <hip/hip_runtime.h>
#include <math.h>

#define IOU_THR 0.5f
#define NCNT 8            // counting blocks in prep_kernel
#define FS 8              // fallback slices per row == partial-slot stride
#define GS 2              // grouped path: column halves per m-pair
#define TPV 4             // grouped path requires num_targets uniformly == TPV
#define SENT 0x7fffffff

__device__ __forceinline__ bool better(float va, int ia, float vb, int ib) {
    // lax.top_k ordering: higher value first; ties -> lower index first
    return (va > vb) || (va == vb && ia < ib);
}

// merge two desc-sorted stable top3 triples -> (a*, x*)
__device__ __forceinline__ void merge3(float& a0, float& a1, float& a2,
                                       int& x0, int& x1, int& x2,
                                       float b0, float b1, float b2,
                                       int y0, int y1, int y2) {
    bool t0 = better(a0, x0, b0, y0);
    float ov0 = t0 ? a0 : b0;  int oi0 = t0 ? x0 : y0;
    float ahv = t0 ? a1 : a0;  int ahi = t0 ? x1 : x0;
    float a2v = t0 ? a2 : a1;  int a2i = t0 ? x2 : x1;
    float bhv = t0 ? b0 : b1;  int bhi = t0 ? y0 : y1;
    float b2v = t0 ? b1 : b2;  int b2i = t0 ? y1 : y2;
    bool t1 = better(ahv, ahi, bhv, bhi);
    float ov1 = t1 ? ahv : bhv; int oi1 = t1 ? ahi : bhi;
    float cav = t1 ? a2v : ahv; int cai = t1 ? a2i : ahi;
    float cbv = t1 ? bhv : b2v; int cbi = t1 ? bhi : b2i;
    bool t2 = better(cav, cai, cbv, cbi);
    a0 = ov0; a1 = ov1; a2 = t2 ? cav : cbv;
    x0 = oi0; x1 = oi1; x2 = t2 ? cai : cbi;
}

// NCNT+1 blocks x 256 threads.
// Blocks 0..NCNT-1: partial nonzero counts of mask2d (coalesced int4).
// Block NCNT: cumsum of num_targets + scatter + uniformity flag (all == TPV).
__global__ void prep_kernel(const int* __restrict__ num_targets,
                            const int* __restrict__ mask2d,
                            int* __restrict__ scatter,
                            int* __restrict__ counts,
                            int* __restrict__ uniform_flag,
                            int S, int M, int P) {
    const int bid = blockIdx.x;
    const int tid = threadIdx.x;

    if (bid < NCNT) {
        const int P4 = P >> 2;
        const int4* __restrict__ m4 = (const int4*)mask2d;
        int c = 0;
        for (int q = bid * 256 + tid; q < P4; q += NCNT * 256) {
            const int4 v = m4[q];
            c += (v.x != 0) + (v.y != 0) + (v.z != 0) + (v.w != 0);
        }
        if (bid == 0) {
            for (int j = (P4 << 2) + tid; j < P; j += 256)
                c += (mask2d[j] != 0);
        }
        __shared__ int red[256];
        red[tid] = c;
        __syncthreads();
        for (int st = 128; st > 0; st >>= 1) {
            if (tid < st) red[tid] += red[tid + st];
            __syncthreads();
        }
        if (tid == 0) counts[bid] = red[0];
    } else {
        __shared__ int cum[1025];   // supports S <= 1024
        __shared__ int scn[256];
        __shared__ int uni[256];
        const int chunk = (S + 255) / 256;
        const int sbase = tid * chunk;
        int local[4];
        int csum = 0;
        int ok = 1;
        for (int k = 0; k < chunk && k < 4; ++k) {
            int s = sbase + k;
            int v = (s < S) ? num_targets[s] : TPV;
            if (s < S && v != TPV) ok = 0;
            csum += (s < S) ? v : 0;
            local[k] = csum;
        }
        scn[tid] = csum;
        uni[tid] = ok;
        __syncthreads();
        for (int d = 1; d < 256; d <<= 1) {
            int v = scn[tid];
            int add = (tid >= d) ? scn[tid - d] : 0;
            __syncthreads();
            scn[tid] = v + add;
            __syncthreads();
        }
        for (int st = 128; st > 0; st >>= 1) {
            if (tid < st) uni[tid] &= uni[tid + st];
            __syncthreads();
        }
        {
            int excl = scn[tid] - csum;
            for (int k = 0; k < chunk && k < 4; ++k) {
                int s = sbase + k;
                if (s < S) cum[s + 1] = excl + local[k];
            }
            if (tid == 0) cum[0] = 0;
        }
        __syncthreads();
        const int total = cum[S];
        if (tid == 0)
            uniform_flag[0] = (uni[0] && total == M && M == TPV * S) ? 1 : 0;
        for (int m = tid; m < M; m += 256) {
            int mm = m;
            if (mm >= total) mm = (total > 0) ? (total - 1) : 0;  // jnp.repeat pad
            int lo = 0, hi = S - 1;
            while (lo < hi) {
                int mid = (lo + hi) >> 1;
                if (cum[mid + 1] <= mm) lo = mid + 1; else hi = mid;
            }
            scatter[m] = lo;
        }
    }
}

// 1 block x 256 threads. Sets flag; if identity mask + pow2 N, returns.
__global__ void build_kernel(const int* __restrict__ counts,
                             const int* __restrict__ mask2d,
                             int* __restrict__ rcidx,
                             float* __restrict__ starts,
                             float* __restrict__ ends,
                             int* __restrict__ flag,
                             int N, int P) {
    const int tid = threadIdx.x;
    __shared__ int scan[256];

    scan[tid] = (tid < NCNT) ? counts[tid] : 0;
    __syncthreads();
    for (int st = 128; st > 0; st >>= 1) {
        if (tid < st) scan[tid] += scan[tid + st];
        __syncthreads();
    }
    const int K_all = scan[0];
    const int f = (K_all == P && (P & 3) == 0 && (N & (N - 1)) == 0 && N >= 4) ? 1 : 0;
    if (tid == 0) flag[0] = f;
    if (f) return;
    __syncthreads();

    const int per = (P + 255) / 256;
    const int base = tid * per;
    int cnt = 0;
    for (int k = 0; k < per; ++k) {
        int j = base + k;
        if (j < P && mask2d[j] != 0) cnt++;
    }
    scan[tid] = cnt;
    __syncthreads();
    for (int d = 1; d < 256; d <<= 1) {
        int v = scan[tid];
        int add = (tid >= d) ? scan[tid - d] : 0;
        __syncthreads();
        scan[tid] = v + add;
        __syncthreads();
    }
    const int K = scan[255];
    int pos = scan[tid] - cnt;

    const float fN = (float)N;
    for (int k = 0; k < per; ++k) {
        int j = base + k;
        if (j < P && mask2d[j] != 0) {
            int r = j / N;
            int c = j - r * N;
            rcidx[pos]  = j;
            starts[pos] = (float)r / fN;
            ends[pos]   = (float)(c + 1) / fN;
            pos++;
        }
    }
    __syncthreads();
    for (int j = K + tid; j < P; j += 256) {
        rcidx[j]  = 0;
        starts[j] = 0.0f;
        ends[j]   = 1.0f / fN;
    }
}

// Grid = M*FS blocks x 256 threads. (256,4): 128-VGPR cap, 16 waves/CU.
// Grouped path (identity mask + uniform TPV): blocks 0..M-1, each handles an
// m-pair sharing one so/eo row x one column half; stages 16 independent
// dwordx4 per batch so loads overlap (the VGPR-starvation fix).
// Fallback: all M*FS blocks, one (m, slice) each.
__global__ __launch_bounds__(256, 4)
void loss_kernel(const float* __restrict__ start_offset,
                 const float* __restrict__ end_offset,
                 const float* __restrict__ tgt_moments,
                 const int* __restrict__ scatter,
                 const float* __restrict__ iou2ds,
                 const int* __restrict__ rcidx,
                 const float* __restrict__ starts,
                 const float* __restrict__ ends,
                 float* __restrict__ opv, int* __restrict__ opi,
                 double* __restrict__ ops, int* __restrict__ opc,
                 const int* __restrict__ flag,
                 const int* __restrict__ uflag,
                 int P, int M, int N) {
    const int blk = blockIdx.x;
    const int tid = threadIdx.x;
    const int fp  = flag[0];
    const int P4  = P >> 2;
    const bool grouped = fp && uflag[0] && ((M & 1) == 0) &&
                         (P4 % (GS * 256 * 4) == 0);
    const int   lgN  = 31 - __clz(N);      // valid when fp (N pow2)
    const float invN = 1.0f / (float)N;    // exact for pow2 N

#define PROC(ST, v, jj, so_, eo_, A_, B_)                                   \
    do {                                                                    \
        const bool b0 = (v) > v0##ST;                                       \
        const bool b1 = (v) > v1##ST;                                       \
        const bool b2 = (v) > v2##ST;                                       \
        const float nv0 = fmaxf(v0##ST, (v));                               \
        const float nv1 = __builtin_amdgcn_fmed3f((v), v0##ST, v1##ST);     \
        const float nv2 = __builtin_amdgcn_fmed3f((v), v1##ST, v2##ST);     \
        i2##ST = b1 ? i1##ST : (b2 ? (jj) : i2##ST);                        \
        i1##ST = b0 ? i0##ST : (b1 ? (jj) : i1##ST);                        \
        i0##ST = b0 ? (jj) : i0##ST;                                        \
        v0##ST = nv0; v1##ST = nv1; v2##ST = nv2;                           \
        const bool sel = (v) > IOU_THR;                                     \
        const float l_ = fabsf((so_) - (A_)) + fabsf((eo_) - (B_));         \
        ls##ST += sel ? l_ : 0.0f;                                          \
        lc##ST += sel ? 1 : 0;                                              \
    } while (0)

    if (grouped) {
        if (blk >= M) return;
        // decode (m-pair, half); same-XCD swizzle: the two blocks sharing
        // (s, half) sit M/2 apart (multiple of 8 -> same XCD's L2).
        int m0, half;
        const int HM = M >> 1;
        if ((HM & 7) == 0 && (M & 3) == 0) {
            const int g = blk % HM, dup = blk / HM;
            m0 = ((g >> 1) << 2) + (dup << 1);
            half = g & 1;
        } else {
            m0 = blk & ~1;
            half = blk & 1;
        }
        const int m1 = m0 + 1;
        const int s  = scatter[m0];          // pairs share s under uniformity

        const float4* __restrict__ so4 = (const float4*)(start_offset + (size_t)s * P);
        const float4* __restrict__ eo4 = (const float4*)(end_offset   + (size_t)s * P);
        const float4* __restrict__ ioA = (const float4*)(iou2ds + (size_t)m0 * P);
        const float4* __restrict__ ioB = (const float4*)(iou2ds + (size_t)m1 * P);
        const float t00 = tgt_moments[2 * m0],     t10 = tgt_moments[2 * m0 + 1];
        const float t01 = tgt_moments[2 * m1],     t11 = tgt_moments[2 * m1 + 1];

        float v0_0 = -INFINITY, v1_0 = -INFINITY, v2_0 = -INFINITY;
        int   i0_0 = SENT, i1_0 = SENT, i2_0 = SENT;
        float ls_0 = 0.f; int lc_0 = 0;
        float v0_1 = -INFINITY, v1_1 = -INFINITY, v2_1 = -INFINITY;
        int   i0_1 = SENT, i1_1 = SENT, i2_1 = SENT;
        float ls_1 = 0.f; int lc_1 = 0;

#define GELEM(q_, VS, VE, VA, VB)                                           \
    do {                                                                    \
        const int j_ = (q_) << 2;                                           \
        const int r_ = j_ >> lgN;                                           \
        const int c_ = j_ & (N - 1);                                        \
        const float stv = (float)r_ * invN;                                 \
        const float en0 = (float)(c_ + 1) * invN;                           \
        const float en1 = en0 + invN;                                       \
        const float en2 = en0 + 2.0f * invN;                                \
        const float en3 = en0 + 3.0f * invN;                                \
        const float A0_ = t00 - stv, A1_ = t01 - stv;                       \
        PROC(_0, (VA).x, j_ + 0, (VS).x, (VE).x, A0_, t10 - en0);           \
        PROC(_0, (VA).y, j_ + 1, (VS).y, (VE).y, A0_, t10 - en1);           \
        PROC(_0, (VA).z, j_ + 2, (VS).z, (VE).z, A0_, t10 - en2);           \
        PROC(_0, (VA).w, j_ + 3, (VS).w, (VE).w, A0_, t10 - en3);           \
        PROC(_1, (VB).x, j_ + 0, (VS).x, (VE).x, A1_, t11 - en0);           \
        PROC(_1, (VB).y, j_ + 1, (VS).y, (VE).y, A1_, t11 - en1);           \
        PROC(_1, (VB).z, j_ + 2, (VS).z, (VE).z, A1_, t11 - en2);           \
        PROC(_1, (VB).w, j_ + 3, (VS).w, (VE).w, A1_, t11 - en3);           \
    } while (0)

        const int qlen  = P4 / GS;
        const int q0    = half * qlen;
        const int iters = qlen >> 8;          // per-thread iters, stride 256
        for (int b = 0; b < iters; b += 4) {
            const int qq = q0 + b * 256 + tid;
            // stage 16 independent dwordx4 back-to-back (64 data VGPRs)
            const float4 sA = so4[qq],       sB = so4[qq + 256],
                         sC = so4[qq + 512], sD = so4[qq + 768];
            const float4 eA = eo4[qq],       eB = eo4[qq + 256],
                         eC = eo4[qq + 512], eD = eo4[qq + 768];
            const float4 aA = ioA[qq],       aB = ioA[qq + 256],
                         aC = ioA[qq + 512], aD = ioA[qq + 768];
            const float4 bA = ioB[qq],       bB = ioB[qq + 256],
                         bC = ioB[qq + 512], bD = ioB[qq + 768];
            GELEM(qq,       sA, eA, aA, bA);
            GELEM(qq + 256, sB, eB, aB, bB);
            GELEM(qq + 512, sC, eC, aC, bC);
            GELEM(qq + 768, sD, eD, aD, bD);
        }
#undef GELEM

        // wave butterflies per state
        for (int d = 1; d < 64; d <<= 1) {
            float b0v = __shfl_xor(v0_0, d), b1v = __shfl_xor(v1_0, d), b2v = __shfl_xor(v2_0, d);
            int   y0 = __shfl_xor(i0_0, d), y1 = __shfl_xor(i1_0, d), y2 = __shfl_xor(i2_0, d);
            merge3(v0_0, v1_0, v2_0, i0_0, i1_0, i2_0, b0v, b1v, b2v, y0, y1, y2);
        }
        for (int d = 1; d < 64; d <<= 1) {
            float b0v = __shfl_xor(v0_1, d), b1v = __shfl_xor(v1_1, d), b2v = __shfl_xor(v2_1, d);
            int   y0 = __shfl_xor(i0_1, d), y1 = __shfl_xor(i1_1, d), y2 = __shfl_xor(i2_1, d);
            merge3(v0_1, v1_1, v2_1, i0_1, i1_1, i2_1, b0v, b1v, b2v, y0, y1, y2);
        }
        double ds0 = (double)ls_0, ds1 = (double)ls_1;
        for (int d = 1; d < 64; d <<= 1) {
            ds0 += __shfl_xor(ds0, d); ds1 += __shfl_xor(ds1, d);
            lc_0 += __shfl_xor(lc_0, d); lc_1 += __shfl_xor(lc_1, d);
        }

        __shared__ float  wv[4][2][3];
        __shared__ int    wi[4][2][3];
        __shared__ double wsm[4][2];
        __shared__ int    wct[4][2];
        const int wid  = tid >> 6;
        const int lane = tid & 63;
        if (lane == 0) {
            wv[wid][0][0] = v0_0; wv[wid][0][1] = v1_0; wv[wid][0][2] = v2_0;
            wv[wid][1][0] = v0_1; wv[wid][1][1] = v1_1; wv[wid][1][2] = v2_1;
            wi[wid][0][0] = i0_0; wi[wid][0][1] = i1_0; wi[wid][0][2] = i2_0;
            wi[wid][1][0] = i0_1; wi[wid][1][1] = i1_1; wi[wid][1][2] = i2_1;
            wsm[wid][0] = ds0; wsm[wid][1] = ds1;
            wct[wid][0] = lc_0; wct[wid][1] = lc_1;
        }
        __syncthreads();
        if (tid < 2) {
            const int km = tid;                // state 0 -> m0, 1 -> m1
            float a0 = wv[0][km][0], a1 = wv[0][km][1], a2 = wv[0][km][2];
            int   x0 = wi[0][km][0], x1 = wi[0][km][1], x2 = wi[0][km][2];
            double Sm = wsm[0][km];
            int    Cm = wct[0][km];
            for (int w = 1; w < 4; ++w) {
                merge3(a0, a1, a2, x0, x1, x2,
                       wv[w][km][0], wv[w][km][1], wv[w][km][2],
                       wi[w][km][0], wi[w][km][1], wi[w][km][2]);
                Sm += wsm[w][km];
                Cm += wct[w][km];
            }
            const int slot = (km == 0 ? m0 : m1) * FS + half;
            opv[slot * 3 + 0] = a0; opv[slot * 3 + 1] = a1; opv[slot * 3 + 2] = a2;
            opi[slot * 3 + 0] = x0; opi[slot * 3 + 1] = x1; opi[slot * 3 + 2] = x2;
            ops[slot] = Sm;
            opc[slot] = Cm;
        }
        return;
    }

    // ---------------- fallback: one block per (m, slice) --------------------
    const int m  = blk >> 3;                 // FS == 8
    const int sl = blk & (FS - 1);
    if (m >= M) return;
    const int s = scatter[m];
    const float* __restrict__ so_row  = start_offset + (size_t)s * P;
    const float* __restrict__ eo_row  = end_offset   + (size_t)s * P;
    const float* __restrict__ iou_row = iou2ds       + (size_t)m * P;
    const float tgt0 = tgt_moments[2 * m];
    const float tgt1 = tgt_moments[2 * m + 1];

    float v0_0 = -INFINITY, v1_0 = -INFINITY, v2_0 = -INFINITY;
    int   i0_0 = SENT, i1_0 = SENT, i2_0 = SENT;
    float ls_0 = 0.0f; int lc_0 = 0;

    if (fp) {
        const float4* __restrict__ iou4 = (const float4*)iou_row;
        const float4* __restrict__ so4  = (const float4*)so_row;
        const float4* __restrict__ eo4  = (const float4*)eo_row;
        const int q4len = (P4 + FS - 1) / FS;
        const int q0 = sl * q4len;
        const int qe = min(q0 + q4len, P4);
        for (int q = q0 + tid; q < qe; q += 256) {
            const float4 vi = iou4[q];
            const float4 vs = so4[q];
            const float4 ve = eo4[q];
            const int j_ = q << 2;
            const int r_ = j_ >> lgN;
            const int c_ = j_ & (N - 1);
            const float A_  = tgt0 - (float)r_ * invN;
            const float en0 = (float)(c_ + 1) * invN;
            PROC(_0, vi.x, j_ + 0, vs.x, ve.x, A_, tgt1 - en0);
            PROC(_0, vi.y, j_ + 1, vs.y, ve.y, A_, tgt1 - (en0 + invN));
            PROC(_0, vi.z, j_ + 2, vs.z, ve.z, A_, tgt1 - (en0 + 2.0f * invN));
            PROC(_0, vi.w, j_ + 3, vs.w, ve.w, A_, tgt1 - (en0 + 3.0f * invN));
        }
    } else {
        const int plen = (P + FS - 1) / FS;
        const int j0 = sl * plen;
        const int je = min(j0 + plen, P);
        for (int j = j0 + tid; j < je; j += 256) {
            const int   idx = rcidx[j];
            const float v   = iou_row[idx];
            const float A_  = tgt0 - starts[j];
            const float B_  = tgt1 - ends[j];
            PROC(_0, v, j, so_row[j], eo_row[j], A_, B_);
        }
    }
#undef PROC

    for (int d = 1; d < 64; d <<= 1) {
        float b0v = __shfl_xor(v0_0, d), b1v = __shfl_xor(v1_0, d), b2v = __shfl_xor(v2_0, d);
        int   y0 = __shfl_xor(i0_0, d), y1 = __shfl_xor(i1_0, d), y2 = __shfl_xor(i2_0, d);
        merge3(v0_0, v1_0, v2_0, i0_0, i1_0, i2_0, b0v, b1v, b2v, y0, y1, y2);
    }
    double dsum = (double)ls_0;
    for (int d = 1; d < 64; d <<= 1) dsum += __shfl_xor(dsum, d);
    for (int d = 1; d < 64; d <<= 1) lc_0 += __shfl_xor(lc_0, d);

    __shared__ float  fwv[4][3];
    __shared__ int    fwi[4][3];
    __shared__ double fws[4];
    __shared__ int    fwc[4];
    const int wid  = tid >> 6;
    const int lane = tid & 63;
    if (lane == 0) {
        fwv[wid][0] = v0_0; fwv[wid][1] = v1_0; fwv[wid][2] = v2_0;
        fwi[wid][0] = i0_0; fwi[wid][1] = i1_0; fwi[wid][2] = i2_0;
        fws[wid] = dsum; fwc[wid] = lc_0;
    }
    __syncthreads();
    if (tid == 0) {
        float a0 = fwv[0][0], a1 = fwv[0][1], a2 = fwv[0][2];
        int   x0 = fwi[0][0], x1 = fwi[0][1], x2 = fwi[0][2];
        double Sm = fws[0];
        int    Cm = fwc[0];
        for (int w = 1; w < 4; ++w) {
            merge3(a0, a1, a2, x0, x1, x2,
                   fwv[w][0], fwv[w][1], fwv[w][2],
                   fwi[w][0], fwi[w][1], fwi[w][2]);
            Sm += fws[w];
            Cm += fwc[w];
        }
        const int slot = m * FS + sl;
        opv[slot * 3 + 0] = a0; opv[slot * 3 + 1] = a1; opv[slot * 3 + 2] = a2;
        opi[slot * 3 + 0] = x0; opi[slot * 3 + 1] = x1; opi[slot * 3 + 2] = x2;
        ops[slot] = Sm;
        opc[slot] = Cm;
    }
}

// 1 block x 1024 threads: per-m merge of slice partials + top-3 correction,
// then block-wide sum and final division.
__global__ void merge_finalize_kernel(const float* __restrict__ opv,
                                      const int* __restrict__ opi,
                                      const double* __restrict__ ops,
                                      const int* __restrict__ opc,
                                      const float* __restrict__ start_offset,
                                      const float* __restrict__ end_offset,
                                      const float* __restrict__ tgt_moments,
                                      const int* __restrict__ scatter,
                                      const float* __restrict__ starts,
                                      const float* __restrict__ ends,
                                      const int* __restrict__ flag,
                                      const int* __restrict__ uflag,
                                      float* __restrict__ out,
                                      int P, int M, int N) {
    const int tid = threadIdx.x;
    const int fp  = flag[0];
    const int P4  = P >> 2;
    const bool grouped = fp && uflag[0] && ((M & 1) == 0) &&
                         (P4 % (GS * 256 * 4) == 0);
    const int slices = grouped ? GS : FS;
    const int   lgN  = 31 - __clz(N);
    const float invN = 1.0f / (float)N;

    double S = 0.0;
    int    C = 0;
    for (int m = tid; m < M; m += 1024) {
        const int base = m * FS;
        float a0 = opv[base * 3 + 0], a1 = opv[base * 3 + 1], a2 = opv[base * 3 + 2];
        int   x0 = opi[base * 3 + 0], x1 = opi[base * 3 + 1], x2 = opi[base * 3 + 2];
        double Sm = ops[base];
        int    Cm = opc[base];
        for (int sl = 1; sl < slices; ++sl) {
            const int b = base + sl;
            merge3(a0, a1, a2, x0, x1, x2,
                   opv[b * 3 + 0], opv[b * 3 + 1], opv[b * 3 + 2],
                   opi[b * 3 + 0], opi[b * 3 + 1], opi[b * 3 + 2]);
            Sm += ops[b];
            Cm += opc[b];
        }
        const int s = scatter[m];
        const float* __restrict__ so_row = start_offset + (size_t)s * P;
        const float* __restrict__ eo_row = end_offset   + (size_t)s * P;
        const float tgt0 = tgt_moments[2 * m];
        const float tgt1 = tgt_moments[2 * m + 1];
#define ADDTOP(vk, jk)                                                      \
        do {                                                                \
            if ((jk) != SENT && !((vk) > IOU_THR)) {                        \
                float st_, en_;                                             \
                if (fp) {                                                   \
                    int r_ = (jk) >> lgN, c_ = (jk) & (N - 1);              \
                    st_ = (float)r_ * invN; en_ = (float)(c_ + 1) * invN;   \
                } else { st_ = starts[jk]; en_ = ends[jk]; }                \
                Sm += (double)(fabsf(so_row[jk] - (tgt0 - st_)) +           \
                               fabsf(eo_row[jk] - (tgt1 - en_)));           \
                Cm += 1;                                                    \
            }                                                               \
        } while (0)
        ADDTOP(a0, x0);
        ADDTOP(a1, x1);
        ADDTOP(a2, x2);
#undef ADDTOP
        S += Sm;
        C += Cm;
    }

    for (int d = 1; d < 64; d <<= 1) {
        S += __shfl_xor(S, d);
        C += __shfl_xor(C, d);
    }
    __shared__ double sd[16];
    __shared__ int    sc[16];
    const int wid  = tid >> 6;
    const int lane = tid & 63;
    if (lane == 0) { sd[wid] = S; sc[wid] = C; }
    __syncthreads();
    if (tid == 0) {
        double T = 0.0;
        int    Ct = 0;
        for (int w = 0; w < 16; ++w) { T += sd[w]; Ct += sc[w]; }
        out[0] = (float)(T / (double)Ct);
    }
}

extern "C" void kernel_launch(void* const* d_in, const int* in_sizes, int n_in,
                              void* d_out, int out_size, void* d_ws, size_t ws_size,
                              hipStream_t stream) {
    const float* start_offset = (const float*)d_in[0];
    const float* end_offset   = (const float*)d_in[1];
    const float* tgt_moments  = (const float*)d_in[2];
    const int*   num_targets  = (const int*)d_in[3];
    const float* iou2ds       = (const float*)d_in[4];
    const int*   mask2d       = (const int*)d_in[5];   // bool pushed as int32

    const int S = in_sizes[3];
    const int M = in_sizes[2] / 2;
    const int P = in_sizes[0] / S;
    const int NN = in_sizes[5];
    int N = 1;
    while ((long long)N * N < (long long)NN) N++;

    // workspace layout (16B aligned blocks)
    char* ws = (char*)d_ws;
    size_t off = 0;
    const size_t MB = (size_t)M * FS;
    int*    flag    = (int*)(ws + off);    off += 16;
    int*    uflag   = (int*)(ws + off);    off += 16;
    int*    counts  = (int*)(ws + off);    off += (NCNT * 4 + 15) & ~(size_t)15;
    int*    scatter = (int*)(ws + off);    off += ((size_t)M * 4 + 15) & ~(size_t)15;
    int*    rcidx   = (int*)(ws + off);    off += ((size_t)P * 4 + 15) & ~(size_t)15;
    float*  starts  = (float*)(ws + off);  off += ((size_t)P * 4 + 15) & ~(size_t)15;
    float*  ends    = (float*)(ws + off);  off += ((size_t)P * 4 + 15) & ~(size_t)15;
    float*  opv     = (float*)(ws + off);  off += (MB * 12 + 15) & ~(size_t)15;
    int*    opi     = (int*)(ws + off);    off += (MB * 12 + 15) & ~(size_t)15;
    double* ops     = (double*)(ws + off); off += (MB * 8 + 15) & ~(size_t)15;
    int*    opc     = (int*)(ws + off);    off += (MB * 4 + 15) & ~(size_t)15;

    prep_kernel<<<NCNT + 1, 256, 0, stream>>>(num_targets, mask2d, scatter, counts,
                                              uflag, S, M, P);
    build_kernel<<<1, 256, 0, stream>>>(counts, mask2d, rcidx, starts, ends, flag, N, P);
    loss_kernel<<<M * FS, 256, 0, stream>>>(start_offset, end_offset, tgt_moments,
                                            scatter, iou2ds, rcidx, starts, ends,
                                            opv, opi, ops, opc, flag, uflag, P, M, N);
    merge_finalize_kernel<<<1, 1024, 0, stream>>>(opv, opi, ops, opc,
                                                  start_offset, end_offset, tgt_moments,
                                                  scatter, starts, ends, flag, uflag,
                                                  (float*)d_out, P, M, N);
}

// Round 11
// 41.899 us; speedup vs baseline: 2.1158x; 1.0171x over previous
//
#include <hip/hip_runtime.h>
#include <math.h>

#define IOU_THR 0.5f
#define NCNT 8            // counting blocks in prep_kernel
#define SENT 0x7fffffff

__device__ __forceinline__ bool better(float va, int ia, float vb, int ib) {
    // lax.top_k ordering: higher value first; ties -> lower index first
    return (va > vb) || (va == vb && ia < ib);
}

// merge two desc-sorted stable top3 triples -> (a*, x*)
__device__ __forceinline__ void merge3(float& a0, float& a1, float& a2,
                                       int& x0, int& x1, int& x2,
                                       float b0, float b1, float b2,
                                       int y0, int y1, int y2) {
    bool t0 = better(a0, x0, b0, y0);
    float ov0 = t0 ? a0 : b0;  int oi0 = t0 ? x0 : y0;
    float ahv = t0 ? a1 : a0;  int ahi = t0 ? x1 : x0;
    float a2v = t0 ? a2 : a1;  int a2i = t0 ? x2 : x1;
    float bhv = t0 ? b0 : b1;  int bhi = t0 ? y0 : y1;
    float b2v = t0 ? b1 : b2;  int b2i = t0 ? y1 : y2;
    bool t1 = better(ahv, ahi, bhv, bhi);
    float ov1 = t1 ? ahv : bhv; int oi1 = t1 ? ahi : bhi;
    float cav = t1 ? a2v : ahv; int cai = t1 ? a2i : ahi;
    float cbv = t1 ? bhv : b2v; int cbi = t1 ? bhi : b2i;
    bool t2 = better(cav, cai, cbv, cbi);
    a0 = ov0; a1 = ov1; a2 = t2 ? cav : cbv;
    x0 = oi0; x1 = oi1; x2 = t2 ? cai : cbi;
}

// async global->LDS, 16B per lane. LDS dest is wave-uniform base; HW scatters
// lane l to base + l*16. Source address is per-lane.
__device__ __forceinline__ void gload16(const void* g, void* l) {
    __builtin_amdgcn_global_load_lds(
        (const __attribute__((address_space(1))) unsigned int*)g,
        (__attribute__((address_space(3))) unsigned int*)l,
        16, 0, 0);
}

// NCNT+1 blocks x 256 threads (same as round 10, minus uniformity flag).
__global__ void prep_kernel(const int* __restrict__ num_targets,
                            const int* __restrict__ mask2d,
                            int* __restrict__ scatter,
                            int* __restrict__ counts,
                            int S, int M, int P) {
    const int bid = blockIdx.x;
    const int tid = threadIdx.x;

    if (bid < NCNT) {
        const int P4 = P >> 2;
        const int4* __restrict__ m4 = (const int4*)mask2d;
        int c = 0;
        for (int q = bid * 256 + tid; q < P4; q += NCNT * 256) {
            const int4 v = m4[q];
            c += (v.x != 0) + (v.y != 0) + (v.z != 0) + (v.w != 0);
        }
        if (bid == 0) {
            for (int j = (P4 << 2) + tid; j < P; j += 256)
                c += (mask2d[j] != 0);
        }
        __shared__ int red[256];
        red[tid] = c;
        __syncthreads();
        for (int st = 128; st > 0; st >>= 1) {
            if (tid < st) red[tid] += red[tid + st];
            __syncthreads();
        }
        if (tid == 0) counts[bid] = red[0];
    } else {
        __shared__ int cum[1025];   // supports S <= 1024
        __shared__ int scn[256];
        const int chunk = (S + 255) / 256;
        const int sbase = tid * chunk;
        int local[4];
        int csum = 0;
        for (int k = 0; k < chunk && k < 4; ++k) {
            int s = sbase + k;
            int v = (s < S) ? num_targets[s] : 0;
            csum += v;
            local[k] = csum;
        }
        scn[tid] = csum;
        __syncthreads();
        for (int d = 1; d < 256; d <<= 1) {
            int v = scn[tid];
            int add = (tid >= d) ? scn[tid - d] : 0;
            __syncthreads();
            scn[tid] = v + add;
            __syncthreads();
        }
        {
            int excl = scn[tid] - csum;
            for (int k = 0; k < chunk && k < 4; ++k) {
                int s = sbase + k;
                if (s < S) cum[s + 1] = excl + local[k];
            }
            if (tid == 0) cum[0] = 0;
        }
        __syncthreads();
        const int total = cum[S];
        for (int m = tid; m < M; m += 256) {
            int mm = m;
            if (mm >= total) mm = (total > 0) ? (total - 1) : 0;  // jnp.repeat pad
            int lo = 0, hi = S - 1;
            while (lo < hi) {
                int mid = (lo + hi) >> 1;
                if (cum[mid + 1] <= mm) lo = mid + 1; else hi = mid;
            }
            scatter[m] = lo;
        }
    }
}

// 1 block x 256 threads. Sets flag; if identity mask + pow2 N, returns.
__global__ void build_kernel(const int* __restrict__ counts,
                             const int* __restrict__ mask2d,
                             int* __restrict__ rcidx,
                             float* __restrict__ starts,
                             float* __restrict__ ends,
                             int* __restrict__ flag,
                             int N, int P) {
    const int tid = threadIdx.x;
    __shared__ int scan[256];

    scan[tid] = (tid < NCNT) ? counts[tid] : 0;
    __syncthreads();
    for (int st = 128; st > 0; st >>= 1) {
        if (tid < st) scan[tid] += scan[tid + st];
        __syncthreads();
    }
    const int K_all = scan[0];
    const int f = (K_all == P && (P & 3) == 0 && (N & (N - 1)) == 0 && N >= 4) ? 1 : 0;
    if (tid == 0) flag[0] = f;
    if (f) return;
    __syncthreads();

    const int per = (P + 255) / 256;
    const int base = tid * per;
    int cnt = 0;
    for (int k = 0; k < per; ++k) {
        int j = base + k;
        if (j < P && mask2d[j] != 0) cnt++;
    }
    scan[tid] = cnt;
    __syncthreads();
    for (int d = 1; d < 256; d <<= 1) {
        int v = scan[tid];
        int add = (tid >= d) ? scan[tid - d] : 0;
        __syncthreads();
        scan[tid] = v + add;
        __syncthreads();
    }
    const int K = scan[255];
    int pos = scan[tid] - cnt;

    const float fN = (float)N;
    for (int k = 0; k < per; ++k) {
        int j = base + k;
        if (j < P && mask2d[j] != 0) {
            int r = j / N;
            int c = j - r * N;
            rcidx[pos]  = j;
            starts[pos] = (float)r / fN;
            ends[pos]   = (float)(c + 1) / fN;
            pos++;
        }
    }
    __syncthreads();
    for (int j = K + tid; j < P; j += 256) {
        rcidx[j]  = 0;
        starts[j] = 0.0f;
        ends[j]   = 1.0f / fN;
    }
}

// Grid = M blocks x 256 threads (4 waves). Deep path: wave-private
// double-buffered LDS staging via global_load_lds (DMA queue holds the
// in-flight data -> MLP without VGPRs). No barriers in the main loop;
// counted vmcnt(6), never 0 mid-loop.
__global__ __launch_bounds__(256)
void loss_kernel(const float* __restrict__ start_offset,
                 const float* __restrict__ end_offset,
                 const float* __restrict__ tgt_moments,
                 const int* __restrict__ scatter,
                 const float* __restrict__ iou2ds,
                 const int* __restrict__ rcidx,
                 const float* __restrict__ starts,
                 const float* __restrict__ ends,
                 double* __restrict__ psum,
                 int* __restrict__ pcnt,
                 const int* __restrict__ flag,
                 int P, int M, int N) {
    // XCD swizzle: the 4 consecutive m sharing one so/eo row land on one XCD.
    const int bid = blockIdx.x;
    const int m = ((M & 7) == 0) ? ((bid & 7) * (M >> 3) + (bid >> 3)) : bid;
    const int tid = threadIdx.x;
    const int fp  = flag[0];
    const int s   = scatter[m];

    const float* __restrict__ so_row  = start_offset + (size_t)s * P;
    const float* __restrict__ eo_row  = end_offset   + (size_t)s * P;
    const float* __restrict__ iou_row = iou2ds       + (size_t)m * P;
    const float tgt0 = tgt_moments[2 * m];
    const float tgt1 = tgt_moments[2 * m + 1];

    const int   lgN  = 31 - __clz(N);      // valid when fp (N pow2)
    const float invN = 1.0f / (float)N;    // exact for pow2 N

    float v0 = -INFINITY, v1 = -INFINITY, v2 = -INFINITY;
    int   i0 = SENT, i1 = SENT, i2 = SENT;
    float lsum = 0.0f;
    int   lcnt = 0;

#define PROC(v, jj, so_, eo_, A_, B_)                                       \
    do {                                                                    \
        const bool b0 = (v) > v0;                                           \
        const bool b1 = (v) > v1;                                           \
        const bool b2 = (v) > v2;                                           \
        const float nv0 = fmaxf(v0, (v));                                   \
        const float nv1 = __builtin_amdgcn_fmed3f((v), v0, v1);             \
        const float nv2 = __builtin_amdgcn_fmed3f((v), v1, v2);             \
        i2 = b1 ? i1 : (b2 ? (jj) : i2);                                    \
        i1 = b0 ? i0 : (b1 ? (jj) : i1);                                    \
        i0 = b0 ? (jj) : i0;                                                \
        v0 = nv0; v1 = nv1; v2 = nv2;                                       \
        const bool sel = (v) > IOU_THR;                                     \
        const float l_ = fabsf((so_) - (A_)) + fabsf((eo_) - (B_));         \
        lsum += sel ? l_ : 0.0f;                                            \
        lcnt += sel ? 1 : 0;                                                \
    } while (0)

#define PROC4(vi, vs, ve, qf4)                                              \
    do {                                                                    \
        const int j_ = (qf4) << 2;                                          \
        const int r_ = j_ >> lgN;                                           \
        const int c_ = j_ & (N - 1);                                        \
        const float A_  = tgt0 - (float)r_ * invN;                          \
        const float en0 = (float)(c_ + 1) * invN;                           \
        PROC((vi).x, j_ + 0, (vs).x, (ve).x, A_, tgt1 - en0);               \
        PROC((vi).y, j_ + 1, (vs).y, (ve).y, A_, tgt1 - (en0 + invN));      \
        PROC((vi).z, j_ + 2, (vs).z, (ve).z, A_, tgt1 - (en0 + 2.0f*invN)); \
        PROC((vi).w, j_ + 3, (vs).w, (ve).w, A_, tgt1 - (en0 + 3.0f*invN)); \
    } while (0)

    // staging LDS: 4 waves x 2 buffers x 3 streams x 128 float4 = 48 KB
    __shared__ float4 stg[4][2][3][128];

    const bool deep = fp && ((P & 2047) == 0);

    if (deep) {
        const int wid  = tid >> 6;
        const int lane = tid & 63;
        const float4* __restrict__ io4 = (const float4*)iou_row;
        const float4* __restrict__ so4 = (const float4*)so_row;
        const float4* __restrict__ eo4 = (const float4*)eo_row;
        const int wq0   = wid * (P >> 4);      // wave's base float4 index
        const int iters = (P >> 4) >> 7;       // (P/16)/128 tiles per wave

#define STAGE(B, T)                                                         \
    do {                                                                    \
        const int qb = wq0 + (T) * 128;                                     \
        gload16(io4 + qb + lane,      &stg[wid][B][0][0]);                  \
        gload16(io4 + qb + 64 + lane, &stg[wid][B][0][64]);                 \
        gload16(so4 + qb + lane,      &stg[wid][B][1][0]);                  \
        gload16(so4 + qb + 64 + lane, &stg[wid][B][1][64]);                 \
        gload16(eo4 + qb + lane,      &stg[wid][B][2][0]);                  \
        gload16(eo4 + qb + 64 + lane, &stg[wid][B][2][64]);                 \
    } while (0)

        STAGE(0, 0);
        for (int t = 0; t < iters; ++t) {
            const int b = t & 1;
            if (t + 1 < iters) {
                // drain this wave's LDS reads before DMA overwrites the
                // other buffer, then issue next tile and wait only for the
                // current tile's 6 loads (6 newest stay in flight).
                asm volatile("s_waitcnt lgkmcnt(0)" ::: "memory");
                __builtin_amdgcn_sched_barrier(0);
                STAGE(b ^ 1, t + 1);
                asm volatile("s_waitcnt vmcnt(6)" ::: "memory");
            } else {
                asm volatile("s_waitcnt vmcnt(0)" ::: "memory");
            }
            __builtin_amdgcn_sched_barrier(0);

            const int q  = wq0 + t * 128 + lane;
            const float4 vi0 = stg[wid][b][0][lane];
            const float4 vi1 = stg[wid][b][0][64 + lane];
            const float4 vs0 = stg[wid][b][1][lane];
            const float4 vs1 = stg[wid][b][1][64 + lane];
            const float4 ve0 = stg[wid][b][2][lane];
            const float4 ve1 = stg[wid][b][2][64 + lane];
            PROC4(vi0, vs0, ve0, q);
            PROC4(vi1, vs1, ve1, q + 64);
        }
#undef STAGE
    } else if (fp) {
        const float4* __restrict__ io4 = (const float4*)iou_row;
        const float4* __restrict__ so4 = (const float4*)so_row;
        const float4* __restrict__ eo4 = (const float4*)eo_row;
        const int P4 = P >> 2;
        for (int q = tid; q < P4; q += 256) {
            const float4 vi = io4[q];
            const float4 vs = so4[q];
            const float4 ve = eo4[q];
            PROC4(vi, vs, ve, q);
        }
    } else {
        for (int j = tid; j < P; j += 256) {
            const int   idx = rcidx[j];
            const float v   = iou_row[idx];
            const float A_  = tgt0 - starts[j];
            const float B_  = tgt1 - ends[j];
            PROC(v, j, so_row[j], eo_row[j], A_, B_);
        }
    }
#undef PROC4
#undef PROC

    // ---- wave-level reductions (shuffle butterflies) ----
    for (int d = 1; d < 64; d <<= 1) {
        float b0v = __shfl_xor(v0, d), b1v = __shfl_xor(v1, d), b2v = __shfl_xor(v2, d);
        int   y0 = __shfl_xor(i0, d), y1 = __shfl_xor(i1, d), y2 = __shfl_xor(i2, d);
        merge3(v0, v1, v2, i0, i1, i2, b0v, b1v, b2v, y0, y1, y2);
    }
    double dsum = (double)lsum;
    for (int d = 1; d < 64; d <<= 1) dsum += __shfl_xor(dsum, d);
    for (int d = 1; d < 64; d <<= 1) lcnt += __shfl_xor(lcnt, d);

    // ---- cross-wave merge via tiny LDS ----
    __shared__ float  wv[4][3];
    __shared__ int    wi[4][3];
    __shared__ double wsum[4];
    __shared__ int    wcnt[4];
    const int wid  = tid >> 6;
    const int lane = tid & 63;
    if (lane == 0) {
        wv[wid][0] = v0; wv[wid][1] = v1; wv[wid][2] = v2;
        wi[wid][0] = i0; wi[wid][1] = i1; wi[wid][2] = i2;
        wsum[wid] = dsum; wcnt[wid] = lcnt;
    }
    __syncthreads();

    if (tid == 0) {
        float a0 = wv[0][0], a1 = wv[0][1], a2 = wv[0][2];
        int   x0 = wi[0][0], x1 = wi[0][1], x2 = wi[0][2];
        double Sm = wsum[0];
        int    Cm = wcnt[0];
        for (int w = 1; w < 4; ++w) {
            merge3(a0, a1, a2, x0, x1, x2,
                   wv[w][0], wv[w][1], wv[w][2],
                   wi[w][0], wi[w][1], wi[w][2]);
            Sm += wsum[w];
            Cm += wcnt[w];
        }
        // top-3 entries not already counted by (iou > 0.5)
#define ADDTOP(vk, jk)                                                      \
        do {                                                                \
            if ((jk) != SENT && !((vk) > IOU_THR)) {                        \
                float st_, en_;                                             \
                if (fp) {                                                   \
                    int r_ = (jk) >> lgN, c_ = (jk) & (N - 1);              \
                    st_ = (float)r_ * invN; en_ = (float)(c_ + 1) * invN;   \
                } else { st_ = starts[jk]; en_ = ends[jk]; }                \
                Sm += (double)(fabsf(so_row[jk] - (tgt0 - st_)) +           \
                               fabsf(eo_row[jk] - (tgt1 - en_)));           \
                Cm += 1;                                                    \
            }                                                               \
        } while (0)
        ADDTOP(a0, x0);
        ADDTOP(a1, x1);
        ADDTOP(a2, x2);
#undef ADDTOP
        psum[m] = Sm;
        pcnt[m] = Cm;
    }
}

__global__ void finalize_kernel(const double* __restrict__ psum,
                                const int* __restrict__ pcnt,
                                int M, float* __restrict__ out) {
    __shared__ double sd[256];
    __shared__ int    sc[256];
    const int tid = threadIdx.x;
    double a = 0.0;
    int    c = 0;
    for (int i = tid; i < M; i += 256) { a += psum[i]; c += pcnt[i]; }
    sd[tid] = a; sc[tid] = c;
    __syncthreads();
    for (int str = 128; str > 0; str >>= 1) {
        if (tid < str) { sd[tid] += sd[tid + str]; sc[tid] += sc[tid + str]; }
        __syncthreads();
    }
    if (tid == 0) out[0] = (float)(sd[0] / (double)sc[0]);
}

extern "C" void kernel_launch(void* const* d_in, const int* in_sizes, int n_in,
                              void* d_out, int out_size, void* d_ws, size_t ws_size,
                              hipStream_t stream) {
    const float* start_offset = (const float*)d_in[0];
    const float* end_offset   = (const float*)d_in[1];
    const float* tgt_moments  = (const float*)d_in[2];
    const int*   num_targets  = (const int*)d_in[3];
    const float* iou2ds       = (const float*)d_in[4];
    const int*   mask2d       = (const int*)d_in[5];   // bool pushed as int32

    const int S = in_sizes[3];
    const int M = in_sizes[2] / 2;
    const int P = in_sizes[0] / S;
    const int NN = in_sizes[5];
    int N = 1;
    while ((long long)N * N < (long long)NN) N++;

    // workspace layout (16B aligned blocks)
    char* ws = (char*)d_ws;
    size_t off = 0;
    int*    flag    = (int*)(ws + off);    off += 16;
    int*    counts  = (int*)(ws + off);    off += (NCNT * 4 + 15) & ~(size_t)15;
    int*    scatter = (int*)(ws + off);    off += ((size_t)M * 4 + 15) & ~(size_t)15;
    int*    rcidx   = (int*)(ws + off);    off += ((size_t)P * 4 + 15) & ~(size_t)15;
    float*  starts  = (float*)(ws + off);  off += ((size_t)P * 4 + 15) & ~(size_t)15;
    float*  ends    = (float*)(ws + off);  off += ((size_t)P * 4 + 15) & ~(size_t)15;
    double* psum    = (double*)(ws + off); off += ((size_t)M * 8 + 15) & ~(size_t)15;
    int*    pcnt    = (int*)(ws + off);    off += ((size_t)M * 4 + 15) & ~(size_t)15;

    prep_kernel<<<NCNT + 1, 256, 0, stream>>>(num_targets, mask2d, scatter, counts,
                                              S, M, P);
    build_kernel<<<1, 256, 0, stream>>>(counts, mask2d, rcidx, starts, ends, flag, N, P);
    loss_kernel<<<M, 256, 0, stream>>>(start_offset, end_offset, tgt_moments,
                                       scatter, iou2ds, rcidx, starts, ends,
                                       psum, pcnt, flag, P, M, N);
    finalize_kernel<<<1, 256, 0, stream>>>(psum, pcnt, M, (float*)d_out);
}

// Round 12
// 40.034 us; speedup vs baseline: 2.2144x; 1.0466x over previous
//
#include <hip/hip_runtime.h>
#include <math.h>

#define IOU_THR 0.5f
#define NCNT 8            // counting blocks in prep_kernel
#define THREADS 512
#define NW (THREADS / 64)
#define TPV 4             // grouped path requires num_targets uniformly == TPV
#define SENT 0x7fffffff

__device__ __forceinline__ bool better(float va, int ia, float vb, int ib) {
    // lax.top_k ordering: higher value first; ties -> lower index first
    return (va > vb) || (va == vb && ia < ib);
}

// merge two desc-sorted stable top3 triples -> (a*, x*)
__device__ __forceinline__ void merge3(float& a0, float& a1, float& a2,
                                       int& x0, int& x1, int& x2,
                                       float b0, float b1, float b2,
                                       int y0, int y1, int y2) {
    bool t0 = better(a0, x0, b0, y0);
    float ov0 = t0 ? a0 : b0;  int oi0 = t0 ? x0 : y0;
    float ahv = t0 ? a1 : a0;  int ahi = t0 ? x1 : x0;
    float a2v = t0 ? a2 : a1;  int a2i = t0 ? x2 : x1;
    float bhv = t0 ? b0 : b1;  int bhi = t0 ? y0 : y1;
    float b2v = t0 ? b1 : b2;  int b2i = t0 ? y1 : y2;
    bool t1 = better(ahv, ahi, bhv, bhi);
    float ov1 = t1 ? ahv : bhv; int oi1 = t1 ? ahi : bhi;
    float cav = t1 ? a2v : ahv; int cai = t1 ? a2i : ahi;
    float cbv = t1 ? bhv : b2v; int cbi = t1 ? bhi : b2i;
    bool t2 = better(cav, cai, cbv, cbi);
    a0 = ov0; a1 = ov1; a2 = t2 ? cav : cbv;
    x0 = oi0; x1 = oi1; x2 = t2 ? cai : cbi;
}

// NCNT+1 blocks x 256 threads.
__global__ void prep_kernel(const int* __restrict__ num_targets,
                            const int* __restrict__ mask2d,
                            int* __restrict__ scatter,
                            int* __restrict__ counts,
                            int* __restrict__ uniform_flag,
                            int S, int M, int P) {
    const int bid = blockIdx.x;
    const int tid = threadIdx.x;

    if (bid < NCNT) {
        const int P4 = P >> 2;
        const int4* __restrict__ m4 = (const int4*)mask2d;
        int c = 0;
        for (int q = bid * 256 + tid; q < P4; q += NCNT * 256) {
            const int4 v = m4[q];
            c += (v.x != 0) + (v.y != 0) + (v.z != 0) + (v.w != 0);
        }
        if (bid == 0) {
            for (int j = (P4 << 2) + tid; j < P; j += 256)
                c += (mask2d[j] != 0);
        }
        __shared__ int red[256];
        red[tid] = c;
        __syncthreads();
        for (int st = 128; st > 0; st >>= 1) {
            if (tid < st) red[tid] += red[tid + st];
            __syncthreads();
        }
        if (tid == 0) counts[bid] = red[0];
    } else {
        __shared__ int cum[1025];   // supports S <= 1024
        __shared__ int scn[256];
        __shared__ int uni[256];
        const int chunk = (S + 255) / 256;
        const int sbase = tid * chunk;
        int local[4];
        int csum = 0;
        int ok = 1;
        for (int k = 0; k < chunk && k < 4; ++k) {
            int s = sbase + k;
            int v = (s < S) ? num_targets[s] : TPV;
            if (s < S && v != TPV) ok = 0;
            csum += (s < S) ? v : 0;
            local[k] = csum;
        }
        scn[tid] = csum;
        uni[tid] = ok;
        __syncthreads();
        for (int d = 1; d < 256; d <<= 1) {
            int v = scn[tid];
            int add = (tid >= d) ? scn[tid - d] : 0;
            __syncthreads();
            scn[tid] = v + add;
            __syncthreads();
        }
        for (int st = 128; st > 0; st >>= 1) {
            if (tid < st) uni[tid] &= uni[tid + st];
            __syncthreads();
        }
        {
            int excl = scn[tid] - csum;
            for (int k = 0; k < chunk && k < 4; ++k) {
                int s = sbase + k;
                if (s < S) cum[s + 1] = excl + local[k];
            }
            if (tid == 0) cum[0] = 0;
        }
        __syncthreads();
        const int total = cum[S];
        if (tid == 0)
            uniform_flag[0] = (uni[0] && total == M && M == TPV * S) ? 1 : 0;
        for (int m = tid; m < M; m += 256) {
            int mm = m;
            if (mm >= total) mm = (total > 0) ? (total - 1) : 0;  // jnp.repeat pad
            int lo = 0, hi = S - 1;
            while (lo < hi) {
                int mid = (lo + hi) >> 1;
                if (cum[mid + 1] <= mm) lo = mid + 1; else hi = mid;
            }
            scatter[m] = lo;
        }
    }
}

// 1 block x 256 threads. Sets flag; if identity mask + pow2 N, returns.
__global__ void build_kernel(const int* __restrict__ counts,
                             const int* __restrict__ mask2d,
                             int* __restrict__ rcidx,
                             float* __restrict__ starts,
                             float* __restrict__ ends,
                             int* __restrict__ flag,
                             int N, int P) {
    const int tid = threadIdx.x;
    __shared__ int scan[256];

    scan[tid] = (tid < NCNT) ? counts[tid] : 0;
    __syncthreads();
    for (int st = 128; st > 0; st >>= 1) {
        if (tid < st) scan[tid] += scan[tid + st];
        __syncthreads();
    }
    const int K_all = scan[0];
    const int f = (K_all == P && (P & 3) == 0 && (N & (N - 1)) == 0 && N >= 4) ? 1 : 0;
    if (tid == 0) flag[0] = f;
    if (f) return;
    __syncthreads();

    const int per = (P + 255) / 256;
    const int base = tid * per;
    int cnt = 0;
    for (int k = 0; k < per; ++k) {
        int j = base + k;
        if (j < P && mask2d[j] != 0) cnt++;
    }
    scan[tid] = cnt;
    __syncthreads();
    for (int d = 1; d < 256; d <<= 1) {
        int v = scan[tid];
        int add = (tid >= d) ? scan[tid - d] : 0;
        __syncthreads();
        scan[tid] = v + add;
        __syncthreads();
    }
    const int K = scan[255];
    int pos = scan[tid] - cnt;

    const float fN = (float)N;
    for (int k = 0; k < per; ++k) {
        int j = base + k;
        if (j < P && mask2d[j] != 0) {
            int r = j / N;
            int c = j - r * N;
            rcidx[pos]  = j;
            starts[pos] = (float)r / fN;
            ends[pos]   = (float)(c + 1) / fN;
            pos++;
        }
    }
    __syncthreads();
    for (int j = K + tid; j < P; j += 256) {
        rcidx[j]  = 0;
        starts[j] = 0.0f;
        ends[j]   = 1.0f / fN;
    }
}

// Grid = M blocks x 512 threads, __launch_bounds__(512,8): VGPR<=64,
// 4 blocks/CU = 32 waves/CU (the R6 occupancy shape that hit ~6.2 TB/s).
// Grouped path: block = (pair of consecutive m sharing s, column half);
// streams {iou_m0, iou_m1, so, eo} over P/2 -> logical bytes 192->128 MB.
// Results per (m, half) slot; merge_finalize combines halves.
__global__ __launch_bounds__(THREADS, 8)
void loss_kernel(const float* __restrict__ start_offset,
                 const float* __restrict__ end_offset,
                 const float* __restrict__ tgt_moments,
                 const int* __restrict__ scatter,
                 const float* __restrict__ iou2ds,
                 const int* __restrict__ rcidx,
                 const float* __restrict__ starts,
                 const float* __restrict__ ends,
                 float* __restrict__ opv, int* __restrict__ opi,
                 double* __restrict__ ops, int* __restrict__ opc,
                 const int* __restrict__ flag,
                 const int* __restrict__ uflag,
                 int P, int M, int N) {
    const int bid = blockIdx.x;
    const int tid = threadIdx.x;
    const int fp  = flag[0];
    const int P4  = P >> 2;
    const int HP4 = P4 >> 1;
    const bool grouped = fp && uflag[0] && ((M & 1) == 0) &&
                         ((HP4 % THREADS) == 0);
    const int   lgN  = 31 - __clz(N);      // valid when fp (N pow2)
    const float invN = 1.0f / (float)N;    // exact for pow2 N

#define PROC(ST, v, jj, so_, eo_, A_, B_)                                   \
    do {                                                                    \
        const bool b0 = (v) > v0##ST;                                       \
        const bool b1 = (v) > v1##ST;                                       \
        const bool b2 = (v) > v2##ST;                                       \
        const float nv0 = fmaxf(v0##ST, (v));                               \
        const float nv1 = __builtin_amdgcn_fmed3f((v), v0##ST, v1##ST);     \
        const float nv2 = __builtin_amdgcn_fmed3f((v), v1##ST, v2##ST);     \
        i2##ST = b1 ? i1##ST : (b2 ? (jj) : i2##ST);                        \
        i1##ST = b0 ? i0##ST : (b1 ? (jj) : i1##ST);                        \
        i0##ST = b0 ? (jj) : i0##ST;                                        \
        v0##ST = nv0; v1##ST = nv1; v2##ST = nv2;                           \
        const bool sel = (v) > IOU_THR;                                     \
        const float l_ = fabsf((so_) - (A_)) + fabsf((eo_) - (B_));         \
        ls##ST += sel ? l_ : 0.0f;                                          \
        lc##ST += sel ? 1 : 0;                                              \
    } while (0)

    if (grouped) {
        // XCD swizzle on the block index; idx -> (half, pair):
        // first M/2 indices = half 0 (pairs ascending), rest = half 1.
        int idx = bid;
        if ((M & 7) == 0) idx = (bid & 7) * (M >> 3) + (bid >> 3);
        const int HM   = M >> 1;
        const int half = idx / HM;
        const int pair = idx - half * HM;
        const int m0   = pair * 2;
        const int m1   = m0 + 1;
        const int s    = scatter[m0];       // == scatter[m1] under uniformity

        const float4* __restrict__ so4 = (const float4*)(start_offset + (size_t)s * P);
        const float4* __restrict__ eo4 = (const float4*)(end_offset   + (size_t)s * P);
        const float4* __restrict__ ioA = (const float4*)(iou2ds + (size_t)m0 * P);
        const float4* __restrict__ ioB = (const float4*)(iou2ds + (size_t)m1 * P);
        const float t00 = tgt_moments[2 * m0], t10 = tgt_moments[2 * m0 + 1];
        const float t01 = tgt_moments[2 * m1], t11 = tgt_moments[2 * m1 + 1];

        float v0_0 = -INFINITY, v1_0 = -INFINITY, v2_0 = -INFINITY;
        int   i0_0 = SENT, i1_0 = SENT, i2_0 = SENT;
        float ls_0 = 0.f; int lc_0 = 0;
        float v0_1 = -INFINITY, v1_1 = -INFINITY, v2_1 = -INFINITY;
        int   i0_1 = SENT, i1_1 = SENT, i2_1 = SENT;
        float ls_1 = 0.f; int lc_1 = 0;

        const int q0 = half * HP4;
        const int qe = q0 + HP4;
        for (int q = q0 + tid; q < qe; q += THREADS) {
            const float4 vs = so4[q];
            const float4 ve = eo4[q];
            const float4 va = ioA[q];
            const float4 vb = ioB[q];
            const int j_ = q << 2;
            const int r_ = j_ >> lgN;
            const int c_ = j_ & (N - 1);
            const float stv = (float)r_ * invN;          // exact pow2 scale
            const float en0 = (float)(c_ + 1) * invN;
            const float en1 = en0 + invN;
            const float en2 = en0 + 2.0f * invN;
            const float en3 = en0 + 3.0f * invN;
            const float A0_ = t00 - stv, A1_ = t01 - stv;
            PROC(_0, va.x, j_ + 0, vs.x, ve.x, A0_, t10 - en0);
            PROC(_0, va.y, j_ + 1, vs.y, ve.y, A0_, t10 - en1);
            PROC(_0, va.z, j_ + 2, vs.z, ve.z, A0_, t10 - en2);
            PROC(_0, va.w, j_ + 3, vs.w, ve.w, A0_, t10 - en3);
            PROC(_1, vb.x, j_ + 0, vs.x, ve.x, A1_, t11 - en0);
            PROC(_1, vb.y, j_ + 1, vs.y, ve.y, A1_, t11 - en1);
            PROC(_1, vb.z, j_ + 2, vs.z, ve.z, A1_, t11 - en2);
            PROC(_1, vb.w, j_ + 3, vs.w, ve.w, A1_, t11 - en3);
        }

        // wave butterflies per state
        for (int d = 1; d < 64; d <<= 1) {
            float b0v = __shfl_xor(v0_0, d), b1v = __shfl_xor(v1_0, d), b2v = __shfl_xor(v2_0, d);
            int   y0 = __shfl_xor(i0_0, d), y1 = __shfl_xor(i1_0, d), y2 = __shfl_xor(i2_0, d);
            merge3(v0_0, v1_0, v2_0, i0_0, i1_0, i2_0, b0v, b1v, b2v, y0, y1, y2);
        }
        for (int d = 1; d < 64; d <<= 1) {
            float b0v = __shfl_xor(v0_1, d), b1v = __shfl_xor(v1_1, d), b2v = __shfl_xor(v2_1, d);
            int   y0 = __shfl_xor(i0_1, d), y1 = __shfl_xor(i1_1, d), y2 = __shfl_xor(i2_1, d);
            merge3(v0_1, v1_1, v2_1, i0_1, i1_1, i2_1, b0v, b1v, b2v, y0, y1, y2);
        }
        double ds0 = (double)ls_0, ds1 = (double)ls_1;
        for (int d = 1; d < 64; d <<= 1) {
            ds0 += __shfl_xor(ds0, d); ds1 += __shfl_xor(ds1, d);
            lc_0 += __shfl_xor(lc_0, d); lc_1 += __shfl_xor(lc_1, d);
        }

        __shared__ float  wv[NW][2][3];
        __shared__ int    wix[NW][2][3];
        __shared__ double wsm[NW][2];
        __shared__ int    wct[NW][2];
        const int wid  = tid >> 6;
        const int lane = tid & 63;
        if (lane == 0) {
            wv[wid][0][0] = v0_0; wv[wid][0][1] = v1_0; wv[wid][0][2] = v2_0;
            wv[wid][1][0] = v0_1; wv[wid][1][1] = v1_1; wv[wid][1][2] = v2_1;
            wix[wid][0][0] = i0_0; wix[wid][0][1] = i1_0; wix[wid][0][2] = i2_0;
            wix[wid][1][0] = i0_1; wix[wid][1][1] = i1_1; wix[wid][1][2] = i2_1;
            wsm[wid][0] = ds0; wsm[wid][1] = ds1;
            wct[wid][0] = lc_0; wct[wid][1] = lc_1;
        }
        __syncthreads();
        if (tid < 2) {
            const int km = tid;                // 0 -> m0, 1 -> m1
            float a0 = wv[0][km][0], a1 = wv[0][km][1], a2 = wv[0][km][2];
            int   x0 = wix[0][km][0], x1 = wix[0][km][1], x2 = wix[0][km][2];
            double Sm = wsm[0][km];
            int    Cm = wct[0][km];
            for (int w = 1; w < NW; ++w) {
                merge3(a0, a1, a2, x0, x1, x2,
                       wv[w][km][0], wv[w][km][1], wv[w][km][2],
                       wix[w][km][0], wix[w][km][1], wix[w][km][2]);
                Sm += wsm[w][km];
                Cm += wct[w][km];
            }
            const int slot = ((km == 0 ? m0 : m1) << 1) + half;
            opv[slot * 3 + 0] = a0; opv[slot * 3 + 1] = a1; opv[slot * 3 + 2] = a2;
            opi[slot * 3 + 0] = x0; opi[slot * 3 + 1] = x1; opi[slot * 3 + 2] = x2;
            ops[slot] = Sm;
            opc[slot] = Cm;
        }
        return;
    }

    // ---------------- fallback: one block per m (full row) ------------------
    const int m = bid;
    if (m >= M) return;
    const int s = scatter[m];
    const float* __restrict__ so_row  = start_offset + (size_t)s * P;
    const float* __restrict__ eo_row  = end_offset   + (size_t)s * P;
    const float* __restrict__ iou_row = iou2ds       + (size_t)m * P;
    const float tgt0 = tgt_moments[2 * m];
    const float tgt1 = tgt_moments[2 * m + 1];

    float v0_0 = -INFINITY, v1_0 = -INFINITY, v2_0 = -INFINITY;
    int   i0_0 = SENT, i1_0 = SENT, i2_0 = SENT;
    float ls_0 = 0.0f; int lc_0 = 0;

    if (fp) {
        const float4* __restrict__ iou4 = (const float4*)iou_row;
        const float4* __restrict__ so4  = (const float4*)so_row;
        const float4* __restrict__ eo4  = (const float4*)eo_row;
        for (int q = tid; q < P4; q += THREADS) {
            const float4 vi = iou4[q];
            const float4 vs = so4[q];
            const float4 ve = eo4[q];
            const int j_ = q << 2;
            const int r_ = j_ >> lgN;
            const int c_ = j_ & (N - 1);
            const float A_  = tgt0 - (float)r_ * invN;
            const float en0 = (float)(c_ + 1) * invN;
            PROC(_0, vi.x, j_ + 0, vs.x, ve.x, A_, tgt1 - en0);
            PROC(_0, vi.y, j_ + 1, vs.y, ve.y, A_, tgt1 - (en0 + invN));
            PROC(_0, vi.z, j_ + 2, vs.z, ve.z, A_, tgt1 - (en0 + 2.0f * invN));
            PROC(_0, vi.w, j_ + 3, vs.w, ve.w, A_, tgt1 - (en0 + 3.0f * invN));
        }
    } else {
        for (int j = tid; j < P; j += THREADS) {
            const int   idx = rcidx[j];
            const float v   = iou_row[idx];
            const float A_  = tgt0 - starts[j];
            const float B_  = tgt1 - ends[j];
            PROC(_0, v, j, so_row[j], eo_row[j], A_, B_);
        }
    }
#undef PROC

    for (int d = 1; d < 64; d <<= 1) {
        float b0v = __shfl_xor(v0_0, d), b1v = __shfl_xor(v1_0, d), b2v = __shfl_xor(v2_0, d);
        int   y0 = __shfl_xor(i0_0, d), y1 = __shfl_xor(i1_0, d), y2 = __shfl_xor(i2_0, d);
        merge3(v0_0, v1_0, v2_0, i0_0, i1_0, i2_0, b0v, b1v, b2v, y0, y1, y2);
    }
    double dsum = (double)ls_0;
    for (int d = 1; d < 64; d <<= 1) dsum += __shfl_xor(dsum, d);
    for (int d = 1; d < 64; d <<= 1) lc_0 += __shfl_xor(lc_0, d);

    __shared__ float  fwv[NW][3];
    __shared__ int    fwi[NW][3];
    __shared__ double fws[NW];
    __shared__ int    fwc[NW];
    const int wid  = tid >> 6;
    const int lane = tid & 63;
    if (lane == 0) {
        fwv[wid][0] = v0_0; fwv[wid][1] = v1_0; fwv[wid][2] = v2_0;
        fwi[wid][0] = i0_0; fwi[wid][1] = i1_0; fwi[wid][2] = i2_0;
        fws[wid] = dsum; fwc[wid] = lc_0;
    }
    __syncthreads();
    if (tid == 0) {
        float a0 = fwv[0][0], a1 = fwv[0][1], a2 = fwv[0][2];
        int   x0 = fwi[0][0], x1 = fwi[0][1], x2 = fwi[0][2];
        double Sm = fws[0];
        int    Cm = fwc[0];
        for (int w = 1; w < NW; ++w) {
            merge3(a0, a1, a2, x0, x1, x2,
                   fwv[w][0], fwv[w][1], fwv[w][2],
                   fwi[w][0], fwi[w][1], fwi[w][2]);
            Sm += fws[w];
            Cm += fwc[w];
        }
        const int slot = m << 1;               // even slot; odd slot = neutral
        opv[slot * 3 + 0] = a0; opv[slot * 3 + 1] = a1; opv[slot * 3 + 2] = a2;
        opi[slot * 3 + 0] = x0; opi[slot * 3 + 1] = x1; opi[slot * 3 + 2] = x2;
        ops[slot] = Sm;
        opc[slot] = Cm;
        opv[(slot + 1) * 3 + 0] = -INFINITY;
        opv[(slot + 1) * 3 + 1] = -INFINITY;
        opv[(slot + 1) * 3 + 2] = -INFINITY;
        opi[(slot + 1) * 3 + 0] = SENT;
        opi[(slot + 1) * 3 + 1] = SENT;
        opi[(slot + 1) * 3 + 2] = SENT;
        ops[slot + 1] = 0.0;
        opc[slot + 1] = 0;
    }
}

// 1 block x 1024 threads: per-m merge of the two half slots + top-3
// correction, then block-wide sum and final division.
__global__ void merge_finalize_kernel(const float* __restrict__ opv,
                                      const int* __restrict__ opi,
                                      const double* __restrict__ ops,
                                      const int* __restrict__ opc,
                                      const float* __restrict__ start_offset,
                                      const float* __restrict__ end_offset,
                                      const float* __restrict__ tgt_moments,
                                      const int* __restrict__ scatter,
                                      const float* __restrict__ starts,
                                      const float* __restrict__ ends,
                                      const int* __restrict__ flag,
                                      float* __restrict__ out,
                                      int P, int M, int N) {
    const int tid = threadIdx.x;
    const int fp  = flag[0];
    const int   lgN  = 31 - __clz(N);
    const float invN = 1.0f / (float)N;

    double S = 0.0;
    long long C = 0;
    for (int m = tid; m < M; m += 1024) {
        const int b0 = (m << 1), b1 = b0 + 1;
        float a0 = opv[b0 * 3 + 0], a1 = opv[b0 * 3 + 1], a2 = opv[b0 * 3 + 2];
        int   x0 = opi[b0 * 3 + 0], x1 = opi[b0 * 3 + 1], x2 = opi[b0 * 3 + 2];
        merge3(a0, a1, a2, x0, x1, x2,
               opv[b1 * 3 + 0], opv[b1 * 3 + 1], opv[b1 * 3 + 2],
               opi[b1 * 3 + 0], opi[b1 * 3 + 1], opi[b1 * 3 + 2]);
        double Sm = ops[b0] + ops[b1];
        int    Cm = opc[b0] + opc[b1];

        const int s = scatter[m];
        const float* __restrict__ so_row = start_offset + (size_t)s * P;
        const float* __restrict__ eo_row = end_offset   + (size_t)s * P;
        const float tgt0 = tgt_moments[2 * m];
        const float tgt1 = tgt_moments[2 * m + 1];
#define ADDTOP(vk, jk)                                                      \
        do {                                                                \
            if ((jk) != SENT && !((vk) > IOU_THR)) {                        \
                float st_, en_;                                             \
                if (fp) {                                                   \
                    int r_ = (jk) >> lgN, c_ = (jk) & (N - 1);              \
                    st_ = (float)r_ * invN; en_ = (float)(c_ + 1) * invN;   \
                } else { st_ = starts[jk]; en_ = ends[jk]; }                \
                Sm += (double)(fabsf(so_row[jk] - (tgt0 - st_)) +           \
                               fabsf(eo_row[jk] - (tgt1 - en_)));           \
                Cm += 1;                                                    \
            }                                                               \
        } while (0)
        ADDTOP(a0, x0);
        ADDTOP(a1, x1);
        ADDTOP(a2, x2);
#undef ADDTOP
        S += Sm;
        C += Cm;
    }

    for (int d = 1; d < 64; d <<= 1) {
        S += __shfl_xor(S, d);
        C += __shfl_xor(C, d);
    }
    __shared__ double sd[16];
    __shared__ long long sc[16];
    const int wid  = tid >> 6;
    const int lane = tid & 63;
    if (lane == 0) { sd[wid] = S; sc[wid] = C; }
    __syncthreads();
    if (tid == 0) {
        double T = 0.0;
        long long Ct = 0;
        for (int w = 0; w < 16; ++w) { T += sd[w]; Ct += sc[w]; }
        out[0] = (float)(T / (double)Ct);
    }
}

extern "C" void kernel_launch(void* const* d_in, const int* in_sizes, int n_in,
                              void* d_out, int out_size, void* d_ws, size_t ws_size,
                              hipStream_t stream) {
    const float* start_offset = (const float*)d_in[0];
    const float* end_offset   = (const float*)d_in[1];
    const float* tgt_moments  = (const float*)d_in[2];
    const int*   num_targets  = (const int*)d_in[3];
    const float* iou2ds       = (const float*)d_in[4];
    const int*   mask2d       = (const int*)d_in[5];   // bool pushed as int32

    const int S = in_sizes[3];
    const int M = in_sizes[2] / 2;
    const int P = in_sizes[0] / S;
    const int NN = in_sizes[5];
    int N = 1;
    while ((long long)N * N < (long long)NN) N++;

    // workspace layout (16B aligned blocks)
    char* ws = (char*)d_ws;
    size_t off = 0;
    const size_t SLOTS = (size_t)M * 2;
    int*    flag    = (int*)(ws + off);    off += 16;
    int*    uflag   = (int*)(ws + off);    off += 16;
    int*    counts  = (int*)(ws + off);    off += (NCNT * 4 + 15) & ~(size_t)15;
    int*    scatter = (int*)(ws + off);    off += ((size_t)M * 4 + 15) & ~(size_t)15;
    int*    rcidx   = (int*)(ws + off);    off += ((size_t)P * 4 + 15) & ~(size_t)15;
    float*  starts  = (float*)(ws + off);  off += ((size_t)P * 4 + 15) & ~(size_t)15;
    float*  ends    = (float*)(ws + off);  off += ((size_t)P * 4 + 15) & ~(size_t)15;
    float*  opv     = (float*)(ws + off);  off += (SLOTS * 12 + 15) & ~(size_t)15;
    int*    opi     = (int*)(ws + off);    off += (SLOTS * 12 + 15) & ~(size_t)15;
    double* ops     = (double*)(ws + off); off += (SLOTS * 8 + 15) & ~(size_t)15;
    int*    opc     = (int*)(ws + off);    off += (SLOTS * 4 + 15) & ~(size_t)15;

    prep_kernel<<<NCNT + 1, 256, 0, stream>>>(num_targets, mask2d, scatter, counts,
                                              uflag, S, M, P);
    build_kernel<<<1, 256, 0, stream>>>(counts, mask2d, rcidx, starts, ends, flag, N, P);
    loss_kernel<<<M, THREADS, 0, stream>>>(start_offset, end_offset, tgt_moments,
                                           scatter, iou2ds, rcidx, starts, ends,
                                           opv, opi, ops, opc, flag, uflag, P, M, N);
    merge_finalize_kernel<<<1, 1024, 0, stream>>>(opv, opi, ops, opc,
                                                  start_offset, end_offset, tgt_moments,
                                                  scatter, starts, ends, flag,
                                                  (float*)d_out, P, M, N);
}

// Round 14
// 34.566 us; speedup vs baseline: 2.5647x; 1.1582x over previous
//
#include <hip/hip_runtime.h>
#include <math.h>

#define IOU_THR 0.5f
#define THREADS 512
#define NW (THREADS / 64)
#define SENT 0x7fffffff

typedef float fx4 __attribute__((ext_vector_type(4)));

__device__ __forceinline__ bool better(float va, int ia, float vb, int ib) {
    // lax.top_k ordering: higher value first; ties -> lower index first
    return (va > vb) || (va == vb && ia < ib);
}

// merge two desc-sorted stable top3 triples -> (a*, x*)
__device__ __forceinline__ void merge3(float& a0, float& a1, float& a2,
                                       int& x0, int& x1, int& x2,
                                       float b0, float b1, float b2,
                                       int y0, int y1, int y2) {
    bool t0 = better(a0, x0, b0, y0);
    float ov0 = t0 ? a0 : b0;  int oi0 = t0 ? x0 : y0;
    float ahv = t0 ? a1 : a0;  int ahi = t0 ? x1 : x0;
    float a2v = t0 ? a2 : a1;  int a2i = t0 ? x2 : x1;
    float bhv = t0 ? b0 : b1;  int bhi = t0 ? y0 : y1;
    float b2v = t0 ? b1 : b2;  int b2i = t0 ? y1 : y2;
    bool t1 = better(ahv, ahi, bhv, bhi);
    float ov1 = t1 ? ahv : bhv; int oi1 = t1 ? ahi : bhi;
    float cav = t1 ? a2v : ahv; int cai = t1 ? a2i : ahi;
    float cbv = t1 ? bhv : b2v; int cbi = t1 ? bhi : b2i;
    bool t2 = better(cav, cai, cbv, cbi);
    a0 = ov0; a1 = ov1; a2 = t2 ? cav : cbv;
    x0 = oi0; x1 = oi1; x2 = t2 ? cai : cbi;
}

// nontemporal float4 load (native ext_vector type; HIP_vector_type rejected)
__device__ __forceinline__ float4 ntload4(const float4* p) {
    fx4 v = __builtin_nontemporal_load((const fx4*)p);
    return make_float4(v.x, v.y, v.z, v.w);
}

// ONE block x 1024 threads: mask count + flag, num_targets cumsum + scatter,
// and (rare path) the nonzero compaction. Replaces prep+build (one launch).
__global__ __launch_bounds__(1024)
void init_kernel(const int* __restrict__ num_targets,
                 const int* __restrict__ mask2d,
                 int* __restrict__ scatter,
                 int* __restrict__ rcidx,
                 float* __restrict__ starts,
                 float* __restrict__ ends,
                 int* __restrict__ flag,
                 int S, int M, int N, int P) {
    const int tid = threadIdx.x;
    __shared__ int red[1024];
    __shared__ int cum[1025];    // supports S <= 1024
    __shared__ int scn[256];

    // ---- Phase A: count mask2d nonzeros (all 1024 threads, int4) ----
    {
        const int P4 = P >> 2;
        const int4* __restrict__ m4 = (const int4*)mask2d;
        int c = 0;
        for (int q = tid; q < P4; q += 1024) {
            const int4 v = m4[q];
            c += (v.x != 0) + (v.y != 0) + (v.z != 0) + (v.w != 0);
        }
        for (int j = (P4 << 2) + tid; j < P; j += 1024)
            c += (mask2d[j] != 0);
        red[tid] = c;
    }
    __syncthreads();
    for (int st = 512; st > 0; st >>= 1) {
        if (tid < st) red[tid] += red[tid + st];
        __syncthreads();
    }
    const int K_all = red[0];
    const int f = (K_all == P && (P & 3) == 0 && (N & (N - 1)) == 0 && N >= 4) ? 1 : 0;
    if (tid == 0) flag[0] = f;

    // ---- Phase B: cumsum of num_targets (threads 0..255) + scatter ----
    if (tid < 256) {
        const int chunk = (S + 255) / 256;   // <= 4 for S <= 1024
        const int sbase = tid * chunk;
        int local[4];
        int csum = 0;
        for (int k = 0; k < chunk && k < 4; ++k) {
            int s = sbase + k;
            int v = (s < S) ? num_targets[s] : 0;
            csum += v;
            local[k] = csum;
        }
        scn[tid] = csum;
        __syncthreads();
        for (int d = 1; d < 256; d <<= 1) {
            int v = scn[tid];
            int add = (tid >= d) ? scn[tid - d] : 0;
            __syncthreads();
            scn[tid] = v + add;
            __syncthreads();
        }
        int excl = scn[tid] - csum;
        for (int k = 0; k < chunk && k < 4; ++k) {
            int s = sbase + k;
            if (s < S) cum[s + 1] = excl + local[k];
        }
        if (tid == 0) cum[0] = 0;
    } else {
        // must participate in the same __syncthreads sequence as tid<256
        __syncthreads();
        for (int d = 1; d < 256; d <<= 1) { __syncthreads(); __syncthreads(); }
    }
    __syncthreads();
    const int total = cum[S];
    for (int m = tid; m < M; m += 1024) {
        int mm = m;
        if (mm >= total) mm = (total > 0) ? (total - 1) : 0;  // jnp.repeat pad
        int lo = 0, hi = S - 1;
        while (lo < hi) {
            int mid = (lo + hi) >> 1;
            if (cum[mid + 1] <= mm) lo = mid + 1; else hi = mid;
        }
        scatter[m] = lo;
    }
    if (f) return;      // identity mask: no compaction tables needed
    __syncthreads();

    // ---- Phase C (rare): compaction via parallel scan (threads 0..255) ----
    if (tid < 256) {
        const int per = (P + 255) / 256;
        const int base = tid * per;
        int cnt = 0;
        for (int k = 0; k < per; ++k) {
            int j = base + k;
            if (j < P && mask2d[j] != 0) cnt++;
        }
        scn[tid] = cnt;
        __syncthreads();
        for (int d = 1; d < 256; d <<= 1) {
            int v = scn[tid];
            int add = (tid >= d) ? scn[tid - d] : 0;
            __syncthreads();
            scn[tid] = v + add;
            __syncthreads();
        }
        const int K = scn[255];
        int pos = scn[tid] - cnt;
        const float fN = (float)N;
        for (int k = 0; k < per; ++k) {
            int j = base + k;
            if (j < P && mask2d[j] != 0) {
                int r = j / N;
                int c = j - r * N;
                rcidx[pos]  = j;
                starts[pos] = (float)r / fN;   // exact reference op
                ends[pos]   = (float)(c + 1) / fN;
                pos++;
            }
        }
        __syncthreads();
        for (int j = K + tid; j < P; j += 256) {   // nonzero(size=P) pads w/ 0
            rcidx[j]  = 0;
            starts[j] = 0.0f;
            ends[j]   = 1.0f / fN;
        }
    }
}

// One block (512 threads) per target row m — the R6 best-measured shape.
// (512,8): 4 blocks/CU = 32 waves/CU. XCD swizzle co-locates the 4 m's
// sharing one so/eo row -> L2 dedups re-reads (cross-L2 = 128 MB floor).
// iou is read-once -> nontemporal so it doesn't evict so/eo lines from L2.
__global__ __launch_bounds__(THREADS, 8)
void loss_kernel(const float* __restrict__ start_offset,
                 const float* __restrict__ end_offset,
                 const float* __restrict__ tgt_moments,
                 const int* __restrict__ scatter,
                 const float* __restrict__ iou2ds,
                 const int* __restrict__ rcidx,
                 const float* __restrict__ starts,
                 const float* __restrict__ ends,
                 double* __restrict__ psum,
                 int* __restrict__ pcnt,
                 const int* __restrict__ flag,
                 int P, int M, int N) {
    const int bid = blockIdx.x;
    const int m = ((M & 7) == 0) ? ((bid & 7) * (M >> 3) + (bid >> 3)) : bid;
    const int tid = threadIdx.x;
    const int fp  = flag[0];
    const int s   = scatter[m];

    const float* __restrict__ so_row  = start_offset + (size_t)s * P;
    const float* __restrict__ eo_row  = end_offset   + (size_t)s * P;
    const float* __restrict__ iou_row = iou2ds       + (size_t)m * P;
    const float tgt0 = tgt_moments[2 * m];
    const float tgt1 = tgt_moments[2 * m + 1];

    const int   lgN  = 31 - __clz(N);       // valid when fp (N pow2)
    const float invN = 1.0f / (float)N;     // exact for pow2 N

    float lsum = 0.0f;
    int   lcnt = 0;

    // thread-local top-3 (sorted desc). Within a thread j strictly increases,
    // so STRICT > compares realize lax.top_k's lowest-index-on-tie semantics.
    float v0 = -INFINITY, v1 = -INFINITY, v2 = -INFINITY;
    int   i0 = SENT, i1 = SENT, i2 = SENT;

#define PROC(v, jj, so_, eo_, A_, B_)                                       \
    do {                                                                    \
        const bool b0 = (v) > v0;                                           \
        const bool b1 = (v) > v1;                                           \
        const bool b2 = (v) > v2;                                           \
        const float nv0 = fmaxf(v0, (v));                                   \
        const float nv1 = __builtin_amdgcn_fmed3f((v), v0, v1);             \
        const float nv2 = __builtin_amdgcn_fmed3f((v), v1, v2);             \
        i2 = b1 ? i1 : (b2 ? (jj) : i2);                                    \
        i1 = b0 ? i0 : (b1 ? (jj) : i1);                                    \
        i0 = b0 ? (jj) : i0;                                                \
        v0 = nv0; v1 = nv1; v2 = nv2;                                       \
        const bool sel = (v) > IOU_THR;                                     \
        const float l_ = fabsf((so_) - (A_)) + fabsf((eo_) - (B_));         \
        lsum += sel ? l_ : 0.0f;                                            \
        lcnt += sel ? 1 : 0;                                                \
    } while (0)

#define PROC4(vi, vs, ve, q)                                                \
    do {                                                                    \
        const int j_  = (q) << 2;                                           \
        const int r_  = j_ >> lgN;                                          \
        const int c_  = j_ & (N - 1);                                       \
        const float A_  = tgt0 - (float)r_ * invN;   /* same row for 4 */   \
        const float en0 = (float)(c_ + 1) * invN;    /* exact pow2 scale */ \
        PROC((vi).x, j_ + 0, (vs).x, (ve).x, A_, tgt1 - en0);               \
        PROC((vi).y, j_ + 1, (vs).y, (ve).y, A_, tgt1 - (en0 + invN));      \
        PROC((vi).z, j_ + 2, (vs).z, (ve).z, A_, tgt1 - (en0 + 2.0f*invN)); \
        PROC((vi).w, j_ + 3, (vs).w, (ve).w, A_, tgt1 - (en0 + 3.0f*invN)); \
    } while (0)

    if (fp && (P & (8 * THREADS - 1)) == 0) {
        // R6 batched fast path: 8 elements (two float4 slabs) per iteration.
        const float4* __restrict__ iou4 = (const float4*)iou_row;
        const float4* __restrict__ so4  = (const float4*)so_row;
        const float4* __restrict__ eo4  = (const float4*)eo_row;
        const int ITERS = P / (8 * THREADS);
        int qA = tid;
        for (int it = 0; it < ITERS; ++it) {
            const int qB = qA + THREADS;
            const float4 iA = ntload4(iou4 + qA); const float4 iB = ntload4(iou4 + qB);
            const float4 sA = so4[qA];  const float4 sB = so4[qB];
            const float4 eA = eo4[qA];  const float4 eB = eo4[qB];
            PROC4(iA, sA, eA, qA);
            PROC4(iB, sB, eB, qB);
            qA += 2 * THREADS;
        }
    } else if (fp) {
        const float4* __restrict__ iou4 = (const float4*)iou_row;
        const float4* __restrict__ so4  = (const float4*)so_row;
        const float4* __restrict__ eo4  = (const float4*)eo_row;
        const int P4 = P >> 2;
        for (int q = tid; q < P4; q += THREADS) {
            const float4 vi = ntload4(iou4 + q);
            const float4 vs = so4[q];
            const float4 ve = eo4[q];
            PROC4(vi, vs, ve, q);
        }
    } else {
        for (int j = tid; j < P; j += THREADS) {
            const int   idx = rcidx[j];
            const float v   = iou_row[idx];
            const float A_  = tgt0 - starts[j];
            const float B_  = tgt1 - ends[j];
            PROC(v, j, so_row[j], eo_row[j], A_, B_);
        }
    }
#undef PROC4
#undef PROC

    // ---- wave-level reductions (shuffle butterflies, no LDS) ----
    for (int d = 1; d < 64; d <<= 1) {
        float bv0 = __shfl_xor(v0, d), bv1 = __shfl_xor(v1, d), bv2 = __shfl_xor(v2, d);
        int   by0 = __shfl_xor(i0, d), by1 = __shfl_xor(i1, d), by2 = __shfl_xor(i2, d);
        merge3(v0, v1, v2, i0, i1, i2, bv0, bv1, bv2, by0, by1, by2);
    }
    double dsum = (double)lsum;
    for (int d = 1; d < 64; d <<= 1) dsum += __shfl_xor(dsum, d);
    for (int d = 1; d < 64; d <<= 1) lcnt += __shfl_xor(lcnt, d);

    // ---- cross-wave merge via tiny LDS ----
    __shared__ float  wv[NW][3];
    __shared__ int    wi[NW][3];
    __shared__ double wsum[NW];
    __shared__ int    wcnt[NW];
    const int wid  = tid >> 6;
    const int lane = tid & 63;
    if (lane == 0) {
        wv[wid][0] = v0; wv[wid][1] = v1; wv[wid][2] = v2;
        wi[wid][0] = i0; wi[wid][1] = i1; wi[wid][2] = i2;
        wsum[wid] = dsum; wcnt[wid] = lcnt;
    }
    __syncthreads();

    if (tid == 0) {
        float a0 = wv[0][0], a1 = wv[0][1], a2 = wv[0][2];
        int   x0 = wi[0][0], x1 = wi[0][1], x2 = wi[0][2];
        double S = wsum[0];
        int    C = wcnt[0];
        for (int w = 1; w < NW; ++w) {
            merge3(a0, a1, a2, x0, x1, x2,
                   wv[w][0], wv[w][1], wv[w][2],
                   wi[w][0], wi[w][1], wi[w][2]);
            S += wsum[w];
            C += wcnt[w];
        }
        // top-3 entries not already counted by (iou > 0.5)
#define ADDTOP(vk, jk)                                                      \
        do {                                                                \
            if ((jk) != SENT && !((vk) > IOU_THR)) {                        \
                float st_, en_;                                             \
                if (fp) {                                                   \
                    int r_ = (jk) >> lgN, c_ = (jk) & (N - 1);              \
                    st_ = (float)r_ * invN; en_ = (float)(c_ + 1) * invN;   \
                } else { st_ = starts[jk]; en_ = ends[jk]; }                \
                S += (double)(fabsf(so_row[jk] - (tgt0 - st_)) +            \
                              fabsf(eo_row[jk] - (tgt1 - en_)));            \
                C += 1;                                                     \
            }                                                               \
        } while (0)
        ADDTOP(a0, x0);
        ADDTOP(a1, x1);
        ADDTOP(a2, x2);
#undef ADDTOP
        psum[bid] = S;
        pcnt[bid] = C;
    }
}

__global__ void finalize_kernel(const double* __restrict__ psum,
                                const int* __restrict__ pcnt,
                                int M, float* __restrict__ out) {
    __shared__ double sd[256];
    __shared__ int    sc[256];
    const int tid = threadIdx.x;
    double a = 0.0;
    int    c = 0;
    for (int i = tid; i < M; i += 256) { a += psum[i]; c += pcnt[i]; }
    sd[tid] = a; sc[tid] = c;
    __syncthreads();
    for (int str = 128; str > 0; str >>= 1) {
        if (tid < str) { sd[tid] += sd[tid + str]; sc[tid] += sc[tid + str]; }
        __syncthreads();
    }
    if (tid == 0) out[0] = (float)(sd[0] / (double)sc[0]);
}

extern "C" void kernel_launch(void* const* d_in, const int* in_sizes, int n_in,
                              void* d_out, int out_size, void* d_ws, size_t ws_size,
                              hipStream_t stream) {
    const float* start_offset = (const float*)d_in[0];
    const float* end_offset   = (const float*)d_in[1];
    const float* tgt_moments  = (const float*)d_in[2];
    const int*   num_targets  = (const int*)d_in[3];
    const float* iou2ds       = (const float*)d_in[4];
    const int*   mask2d       = (const int*)d_in[5];   // bool pushed as int32

    const int S = in_sizes[3];
    const int M = in_sizes[2] / 2;
    const int P = in_sizes[0] / S;
    const int NN = in_sizes[5];
    int N = 1;
    while ((long long)N * N < (long long)NN) N++;

    // workspace layout (16B aligned blocks)
    char* ws = (char*)d_ws;
    size_t off = 0;
    int*    flag    = (int*)(ws + off);    off += 16;
    int*    scatter = (int*)(ws + off);    off += ((size_t)M * 4 + 15) & ~(size_t)15;
    int*    rcidx   = (int*)(ws + off);    off += ((size_t)P * 4 + 15) & ~(size_t)15;
    float*  starts  = (float*)(ws + off);  off += ((size_t)P * 4 + 15) & ~(size_t)15;
    float*  ends    = (float*)(ws + off);  off += ((size_t)P * 4 + 15) & ~(size_t)15;
    double* psum    = (double*)(ws + off); off += ((size_t)M * 8 + 15) & ~(size_t)15;
    int*    pcnt    = (int*)(ws + off);    off += ((size_t)M * 4 + 15) & ~(size_t)15;

    init_kernel<<<1, 1024, 0, stream>>>(num_targets, mask2d, scatter, rcidx,
                                        starts, ends, flag, S, M, N, P);
    loss_kernel<<<M, THREADS, 0, stream>>>(start_offset, end_offset, tgt_moments,
                                           scatter, iou2ds, rcidx, starts, ends,
                                           psum, pcnt, flag, P, M, N);
    finalize_kernel<<<1, 256, 0, stream>>>(psum, pcnt, M, (float*)d_out);
}